// Round 1
// baseline (536.548 us; speedup 1.0000x reference)
//
#include <hip/hip_runtime.h>
#include <math.h>

#define INV_2PI  0.15915494309189535f
#define TWO_PI_F 6.283185307179586f
// DT/(2*pi)/N = 0.01/(2*pi)/192
#define FSCALE   8.2893199e-06f

// ============================ prep ============================
// Ksym = (IC + IC^T)/2 ; om_eff = omega*DT/(2pi) ; zero binding accumulators
__global__ __launch_bounds__(256) void prep_kernel(
    const float* __restrict__ IC,
    const float* __restrict__ oa, const float* __restrict__ ot, const float* __restrict__ ov,
    float* __restrict__ Ksym, float* __restrict__ om_eff, float* __restrict__ bacc)
{
    int t = blockIdx.x * 256 + threadIdx.x;
    for (int idx = t; idx < 192 * 192; idx += 64 * 256) {
        int i = idx / 192, j = idx - i * 192;
        Ksym[idx] = 0.5f * (IC[idx] + IC[j * 192 + i]);
    }
    if (blockIdx.x == 0) {
        int tt = threadIdx.x;
        if (tt < 192) {
            float w = tt < 64 ? oa[tt] : (tt < 128 ? ot[tt - 64] : ov[tt - 128]);
            om_eff[tt] = w * (0.01f * INV_2PI);
        }
        if (tt < 4) bacc[tt] = 0.f;
    }
}

// ============================ tiled NT GEMM ============================
// C[m][n] = sum_k A[m][k]*W[n][k] + bias[n]
// BM=BN=64, BK=16, 256 threads, 4x4 micro-tile. z = blockIdx.z selects modality.
// mode 0: plain store. mode 1: store fract(v/2pi) (phase init, revolutions).
// mode 2: A scaled at load by scale[m][k>>8] (fusion GEMM).
__global__ __launch_bounds__(256) void gemm3_kernel(
    const float* __restrict__ A0, const float* __restrict__ A1, const float* __restrict__ A2,
    const float* __restrict__ W0, const float* __restrict__ W1, const float* __restrict__ W2,
    const float* __restrict__ B0, const float* __restrict__ B1, const float* __restrict__ B2,
    int K0, int K1, int K2,
    float* __restrict__ C, int ldc, int colstride,
    int mode, const float* __restrict__ scale)
{
    int z = blockIdx.z;
    const float* A    = z == 0 ? A0 : (z == 1 ? A1 : A2);
    const float* W    = z == 0 ? W0 : (z == 1 ? W1 : W2);
    const float* bias = z == 0 ? B0 : (z == 1 ? B1 : B2);
    int K             = z == 0 ? K0 : (z == 1 ? K1 : K2);

    int m0 = blockIdx.x * 64, n0 = blockIdx.y * 64;
    int t  = threadIdx.x;
    int tx = t & 15, ty = t >> 4;

    // pad 68: 16B-aligned f4 reads, only 2-4 way write aliasing (cheap)
    __shared__ float As[16][68];
    __shared__ float Bs[16][68];

    float acc[4][4] = {};
    int lk = t & 15;   // k within tile (load)
    int lm = t >> 4;   // base row (load), 4 passes of 16 rows

    for (int k0 = 0; k0 < K; k0 += 16) {
#pragma unroll
        for (int j = 0; j < 4; ++j) {
            int m = lm + 16 * j;
            float v = A[(size_t)(m0 + m) * K + k0 + lk];
            if (mode == 2) v *= scale[(size_t)(m0 + m) * 3 + ((k0 + lk) >> 8)];
            As[lk][m] = v;
            Bs[lk][m] = W[(size_t)(n0 + m) * K + k0 + lk];
        }
        __syncthreads();
#pragma unroll
        for (int kk = 0; kk < 16; ++kk) {
            float4 a = *(const float4*)&As[kk][ty * 4];
            float4 b = *(const float4*)&Bs[kk][tx * 4];
            float av[4] = {a.x, a.y, a.z, a.w};
            float bv[4] = {b.x, b.y, b.z, b.w};
#pragma unroll
            for (int i = 0; i < 4; ++i)
#pragma unroll
                for (int j = 0; j < 4; ++j)
                    acc[i][j] += av[i] * bv[j];
        }
        __syncthreads();
    }

#pragma unroll
    for (int i = 0; i < 4; ++i) {
        int m = m0 + ty * 4 + i;
#pragma unroll
        for (int j = 0; j < 4; ++j) {
            int n = n0 + tx * 4 + j;
            float v = acc[i][j] + bias[n];
            if (mode == 1) { v *= INV_2PI; v = v - floorf(v); }
            C[(size_t)m * ldc + z * colstride + n] = v;
        }
    }
}

// ============================ Kuramoto ============================
// phases in revolutions. forces_i = (s_i*(K c)_i - c_i*(K s)_i)/N.
// 4 batch rows / block, 256 threads, K staged in 4 col-chunks of 48 (LDS<64KB).
// Thread slot s (3 per thread) owns item = s*256+t -> (r=item/192, i=item%192);
// 64-lane runs never straddle rows (192 = 3*64), so c/s LDS reads broadcast.
__global__ __launch_bounds__(256) void kuramoto_kernel(
    const float* __restrict__ ph_init,   // (B,192) revolutions
    const float* __restrict__ Ksym,      // (192,192) fp32
    const float* __restrict__ om_eff,    // (192) = omega*DT/2pi
    float* __restrict__ phases_out,      // (B,192) radians -> d_out
    float* __restrict__ pmscale,         // (B,3) = 0.5+0.5*mean_cos
    float* __restrict__ bacc)            // 3 pair sums
{
    __shared__ float4 Kch4[192 * 13];    // chunk 192x48 fp32, stride 13 f4 (52 words)
    __shared__ float  csc[4][192];
    __shared__ float  css[4][192];
    __shared__ float  Rl[4][3];

    int t  = threadIdx.x;
    int m0 = blockIdx.x * 4;

    float ph[3], om[3], cr[3], sr[3], aC[3], aS[3];
    int rr[3], ii[3];
#pragma unroll
    for (int s = 0; s < 3; ++s) {
        int item = s * 256 + t;
        rr[s] = item / 192;
        ii[s] = item - rr[s] * 192;
        ph[s] = ph_init[(size_t)(m0 + rr[s]) * 192 + ii[s]];
        om[s] = om_eff[ii[s]];
    }

    const float4* Kg4 = (const float4*)Ksym;   // row stride 48 f4

    for (int step = 0; step < 10; ++step) {
#pragma unroll
        for (int s = 0; s < 3; ++s) {
            cr[s] = __builtin_amdgcn_cosf(ph[s]);
            sr[s] = __builtin_amdgcn_sinf(ph[s]);
            csc[rr[s]][ii[s]] = cr[s];
            css[rr[s]][ii[s]] = sr[s];
            aC[s] = 0.f; aS[s] = 0.f;
        }
        __syncthreads();

        for (int ch = 0; ch < 4; ++ch) {
            // stage chunk: 192 rows x 12 f4 = 2304 f4, 9 per thread
#pragma unroll
            for (int j = 0; j < 9; ++j) {
                int idx = t + j * 256;
                int row = idx / 12, c4 = idx - row * 12;
                Kch4[row * 13 + c4] = Kg4[(size_t)row * 48 + ch * 12 + c4];
            }
            __syncthreads();
#pragma unroll
            for (int s = 0; s < 3; ++s) {
                const float4* Kr = &Kch4[ii[s] * 13];
                const float4* cc = (const float4*)&csc[rr[s]][ch * 48];
                const float4* ss = (const float4*)&css[rr[s]][ch * 48];
#pragma unroll
                for (int q = 0; q < 12; ++q) {
                    float4 k4 = Kr[q];
                    float4 c4 = cc[q];
                    float4 s4 = ss[q];
                    aC[s] += k4.x * c4.x + k4.y * c4.y + k4.z * c4.z + k4.w * c4.w;
                    aS[s] += k4.x * s4.x + k4.y * s4.y + k4.z * s4.z + k4.w * s4.w;
                }
            }
            __syncthreads();
        }
#pragma unroll
        for (int s = 0; s < 3; ++s) {
            float f = (sr[s] * aC[s] - cr[s] * aS[s]) * FSCALE;
            float p = ph[s] + om[s] + f;
            ph[s] = p - floorf(p);
        }
    }

    // final phases (radians) + final cos/sin for binding stats
#pragma unroll
    for (int s = 0; s < 3; ++s) {
        phases_out[(size_t)(m0 + rr[s]) * 192 + ii[s]] = ph[s] * TWO_PI_F;
        csc[rr[s]][ii[s]] = __builtin_amdgcn_cosf(ph[s]);
        css[rr[s]][ii[s]] = __builtin_amdgcn_sinf(ph[s]);
    }
    __syncthreads();

    if (t < 12) {
        int r = t / 3, mod = t - r * 3;
        float sc = 0.f, ss = 0.f;
        for (int k = 0; k < 64; ++k) {
            sc += csc[r][mod * 64 + k];
            ss += css[r][mod * 64 + k];
        }
        sc *= (1.f / 64.f); ss *= (1.f / 64.f);
        float R = sqrtf(sc * sc + ss * ss);
        pmscale[(size_t)(m0 + r) * 3 + mod] = 0.5f + 0.5f * sc;
        Rl[r][mod] = R;
    }
    __syncthreads();
    if (t == 0) {
        float p01 = 0.f, p02 = 0.f, p12 = 0.f;
        for (int r = 0; r < 4; ++r) {
            p01 += Rl[r][0] * Rl[r][1];
            p02 += Rl[r][0] * Rl[r][2];
            p12 += Rl[r][1] * Rl[r][2];
        }
        atomicAdd(&bacc[0], p01);
        atomicAdd(&bacc[1], p02);
        atomicAdd(&bacc[2], p12);
    }
}

// ============================ finalize ============================
__global__ __launch_bounds__(256) void finalize_kernel(
    const float* __restrict__ bacc, float* __restrict__ out_bm, float* __restrict__ out_total)
{
    float p01 = bacc[0] * (1.f / 2048.f);
    float p02 = bacc[1] * (1.f / 2048.f);
    float p12 = bacc[2] * (1.f / 2048.f);
    float total = (p01 + p02 + p12) * (1.f / 3.f);
    int t = threadIdx.x;
    if (t == 0) {
        out_bm[0] = 1.f; out_bm[1] = p01; out_bm[2] = p02;
        out_bm[3] = p01; out_bm[4] = 1.f; out_bm[5] = p12;
        out_bm[6] = p02; out_bm[7] = p12; out_bm[8] = 1.f;
    }
    for (int i = t; i < 2048; i += 256) out_total[i] = total;
}

// ============================ launch ============================
extern "C" void kernel_launch(void* const* d_in, const int* in_sizes, int n_in,
                              void* d_out, int out_size, void* d_ws, size_t ws_size,
                              hipStream_t stream)
{
    const float* x_a  = (const float*)d_in[0];
    const float* Wf_a = (const float*)d_in[1];
    const float* bf_a = (const float*)d_in[2];
    const float* Wp_a = (const float*)d_in[3];
    const float* bp_a = (const float*)d_in[4];
    const float* x_t  = (const float*)d_in[5];
    const float* Wf_t = (const float*)d_in[6];
    const float* bf_t = (const float*)d_in[7];
    const float* Wp_t = (const float*)d_in[8];
    const float* bp_t = (const float*)d_in[9];
    const float* x_v  = (const float*)d_in[10];
    const float* Wf_v = (const float*)d_in[11];
    const float* bf_v = (const float*)d_in[12];
    const float* Wp_v = (const float*)d_in[13];
    const float* bp_v = (const float*)d_in[14];
    const float* om_a = (const float*)d_in[15];
    const float* om_t = (const float*)d_in[16];
    const float* om_v = (const float*)d_in[17];
    const float* IC   = (const float*)d_in[18];
    const float* Wfu  = (const float*)d_in[19];
    const float* bfu  = (const float*)d_in[20];

    float* ws    = (float*)d_ws;
    float* e_all = ws;                 // 2048*768
    float* ph0   = ws + 1572864;       // 2048*192 (revolutions)
    float* Ksym  = ws + 1966080;       // 192*192
    float* omw   = ws + 2002944;       // 192 (+pad)
    float* pm    = ws + 2003200;       // 2048*3
    float* baccw = ws + 2009344;       // 4

    float* out        = (float*)d_out;
    float* out_bound  = out;           // 2048*256
    float* out_bm     = out + 524288;  // 9
    float* out_phases = out + 524297;  // 2048*192
    float* out_total  = out + 917513;  // 2048

    prep_kernel<<<64, 256, 0, stream>>>(IC, om_a, om_t, om_v, Ksym, omw, baccw);

    // encoded = x @ Wf^T + bf  -> e_all (B,768), col block = 256*z
    dim3 gWf(32, 4, 3);
    gemm3_kernel<<<gWf, 256, 0, stream>>>(x_a, x_t, x_v, Wf_a, Wf_t, Wf_v,
                                          bf_a, bf_t, bf_v, 512, 768, 1024,
                                          e_all, 768, 256, 0, nullptr);
    // phases0 = fract((x @ Wp^T + bp)/2pi) -> ph0 (B,192), col block = 64*z
    dim3 gWp(32, 1, 3);
    gemm3_kernel<<<gWp, 256, 0, stream>>>(x_a, x_t, x_v, Wp_a, Wp_t, Wp_v,
                                          bp_a, bp_t, bp_v, 512, 768, 1024,
                                          ph0, 192, 64, 1, nullptr);

    kuramoto_kernel<<<512, 256, 0, stream>>>(ph0, Ksym, omw, out_phases, pm, baccw);

    finalize_kernel<<<1, 256, 0, stream>>>(baccw, out_bm, out_total);

    // bound = (e_all * (0.5+0.5*pm)) @ W_fusion^T + b_fusion
    dim3 gFu(32, 4, 1);
    gemm3_kernel<<<gFu, 256, 0, stream>>>(e_all, e_all, e_all, Wfu, Wfu, Wfu,
                                          bfu, bfu, bfu, 768, 768, 768,
                                          out_bound, 256, 0, 2, pm);
}

// Round 2
// 234.728 us; speedup vs baseline: 2.2858x; 2.2858x over previous
//
#include <hip/hip_runtime.h>
#include <math.h>

typedef short bf16x8 __attribute__((ext_vector_type(8)));
typedef short bf16x4 __attribute__((ext_vector_type(4)));
typedef float f32x4  __attribute__((ext_vector_type(4)));

#define INV_2PI  0.15915494309189535f
#define TWO_PI_F 6.283185307179586f
// DT/(2*pi)/N = 0.01/(2*pi)/192
#define FSCALE   8.2893199e-06f

static __device__ inline short f2bf(float f) {
    union { float f; unsigned u; } v; v.f = f;
    unsigned r = (v.u + 0x7FFFu + ((v.u >> 16) & 1u)) >> 16;
    return (short)r;
}
static __device__ inline float bf2f(short h) {
    union { unsigned u; float f; } v; v.u = ((unsigned)(unsigned short)h) << 16;
    return v.f;
}

// ============================ prep ============================
// Wb = bf16(Wf_a|Wf_t|Wf_v|W_fusion); Kp = bf16 Ksym in 16x16x32 B-frag layout;
// om_eff = omega*DT/2pi; bacc zeroed.
__global__ __launch_bounds__(256) void prep_kernel(
    const float* __restrict__ IC,
    const float* __restrict__ oa, const float* __restrict__ ot, const float* __restrict__ ov,
    const float* __restrict__ Wf_a, const float* __restrict__ Wf_t,
    const float* __restrict__ Wf_v, const float* __restrict__ Wfu,
    short* __restrict__ Wb, short* __restrict__ Kp,
    float* __restrict__ om_eff, float* __restrict__ bacc)
{
    int t = blockIdx.x * 256 + threadIdx.x;
    int nthr = gridDim.x * 256;
    for (int idx = t; idx < 786432; idx += nthr) {
        float v;
        if (idx < 131072)       v = Wf_a[idx];
        else if (idx < 327680)  v = Wf_t[idx - 131072];
        else if (idx < 589824)  v = Wf_v[idx - 327680];
        else                    v = Wfu[idx - 589824];
        Wb[idx] = f2bf(v);
    }
    // B-fragment layout for 16x16x32 bf16: lane holds B[k=kc*32+(lane>>4)*8+j][n=nt*16+(lane&15)]
    for (int idx = t; idx < 36864; idx += nthr) {
        int k = idx / 192, n = idx - k * 192;
        float v = 0.5f * (IC[k * 192 + n] + IC[n * 192 + k]);
        int nt = n >> 4, kc = k >> 5;
        int lane = ((k >> 3) & 3) * 16 + (n & 15);
        int j = k & 7;
        Kp[((nt * 6 + kc) * 64 + lane) * 8 + j] = f2bf(v);
    }
    if (blockIdx.x == 0) {
        int tt = threadIdx.x;
        if (tt < 192) {
            float w = tt < 64 ? oa[tt] : (tt < 128 ? ot[tt - 64] : ov[tt - 128]);
            om_eff[tt] = w * (0.01f * INV_2PI);
        }
        if (tt < 4) bacc[tt] = 0.f;
    }
}

// ============================ encode GEMM (bf16 MFMA) ============================
// e_bf16[m][z*256+n] = bf16( x_z @ Wf_z^T + bf_z ). BM=BN=128, BK=32, 4 waves 2x2,
// wave tile 64x64 as 4x4 grid of 16x16x32 fragments.
__global__ __launch_bounds__(256) void encode_gemm_kernel(
    const float* __restrict__ xa, const float* __restrict__ xt, const float* __restrict__ xv,
    const short* __restrict__ Wb,
    const float* __restrict__ ba, const float* __restrict__ bt, const float* __restrict__ bv,
    short* __restrict__ e_bf16)
{
    int z = blockIdx.z;
    const float* A    = z == 0 ? xa : (z == 1 ? xt : xv);
    const short* W    = z == 0 ? Wb : (z == 1 ? Wb + 131072 : Wb + 327680);
    const float* bias = z == 0 ? ba : (z == 1 ? bt : bv);
    int K             = z == 0 ? 512 : (z == 1 ? 768 : 1024);

    int m0 = blockIdx.x * 128, n0 = blockIdx.y * 128;
    int t = threadIdx.x;
    int lane = t & 63, w = t >> 6;
    int wm = w >> 1, wn = w & 1;
    int q = lane >> 4, col = lane & 15;

    __shared__ alignas(16) short As[128][32];
    __shared__ alignas(16) short Bs[128][32];

    f32x4 acc[4][4];
#pragma unroll
    for (int i = 0; i < 4; ++i)
#pragma unroll
        for (int j = 0; j < 4; ++j)
#pragma unroll
            for (int r = 0; r < 4; ++r) acc[i][j][r] = 0.f;

    for (int k0 = 0; k0 < K; k0 += 32) {
        // stage A: 128x32 fp32 -> bf16
#pragma unroll
        for (int p = 0; p < 4; ++p) {
            int idx = t + 256 * p;
            int row = idx >> 3, c4 = idx & 7;
            float4 v = *(const float4*)&A[(size_t)(m0 + row) * K + k0 + c4 * 4];
            bf16x4 h; h[0] = f2bf(v.x); h[1] = f2bf(v.y); h[2] = f2bf(v.z); h[3] = f2bf(v.w);
            *(bf16x4*)&As[row][c4 * 4] = h;
        }
        // stage B: 128x32 bf16
#pragma unroll
        for (int p = 0; p < 2; ++p) {
            int idx = t + 256 * p;
            int row = idx >> 2, c8 = idx & 3;
            *(bf16x8*)&Bs[row][c8 * 8] = *(const bf16x8*)&W[(size_t)(n0 + row) * K + k0 + c8 * 8];
        }
        __syncthreads();

        bf16x8 af[4], bf[4];
#pragma unroll
        for (int f = 0; f < 4; ++f) {
            af[f] = *(const bf16x8*)&As[wm * 64 + f * 16 + col][q * 8];
            bf[f] = *(const bf16x8*)&Bs[wn * 64 + f * 16 + col][q * 8];
        }
#pragma unroll
        for (int fm = 0; fm < 4; ++fm)
#pragma unroll
            for (int fn = 0; fn < 4; ++fn)
                acc[fm][fn] = __builtin_amdgcn_mfma_f32_16x16x32_bf16(af[fm], bf[fn], acc[fm][fn], 0, 0, 0);
        __syncthreads();
    }

#pragma unroll
    for (int fn = 0; fn < 4; ++fn) {
        int n = n0 + wn * 64 + fn * 16 + col;
        float bn = bias[n];
#pragma unroll
        for (int fm = 0; fm < 4; ++fm)
#pragma unroll
            for (int r = 0; r < 4; ++r) {
                int m = m0 + wm * 64 + fm * 16 + q * 4 + r;
                e_bf16[(size_t)m * 768 + z * 256 + n] = f2bf(acc[fm][fn][r] + bn);
            }
    }
}

// ============================ phase GEMM (fp32, unchanged math) ============================
// ph0[m][z*64+n] = fract((x @ Wp^T + bp)/2pi)   -- kept fp32 for wrap safety.
__global__ __launch_bounds__(256) void phase_gemm_kernel(
    const float* __restrict__ xa, const float* __restrict__ xt, const float* __restrict__ xv,
    const float* __restrict__ Wpa, const float* __restrict__ Wpt, const float* __restrict__ Wpv,
    const float* __restrict__ bpa, const float* __restrict__ bpt, const float* __restrict__ bpv,
    float* __restrict__ ph0)
{
    int z = blockIdx.z;
    const float* A    = z == 0 ? xa : (z == 1 ? xt : xv);
    const float* W    = z == 0 ? Wpa : (z == 1 ? Wpt : Wpv);
    const float* bias = z == 0 ? bpa : (z == 1 ? bpt : bpv);
    int K             = z == 0 ? 512 : (z == 1 ? 768 : 1024);

    int m0 = blockIdx.x * 64, n0 = 0;
    int t = threadIdx.x;
    int tx = t & 15, ty = t >> 4;

    __shared__ float As[16][68];
    __shared__ float Bs[16][68];

    float acc[4][4] = {};
    int lk = t & 15;
    int lm = t >> 4;

    for (int k0 = 0; k0 < K; k0 += 16) {
#pragma unroll
        for (int j = 0; j < 4; ++j) {
            int m = lm + 16 * j;
            As[lk][m] = A[(size_t)(m0 + m) * K + k0 + lk];
            Bs[lk][m] = W[(size_t)(n0 + m) * K + k0 + lk];
        }
        __syncthreads();
#pragma unroll
        for (int kk = 0; kk < 16; ++kk) {
            float4 a = *(const float4*)&As[kk][ty * 4];
            float4 b = *(const float4*)&Bs[kk][tx * 4];
            float av[4] = {a.x, a.y, a.z, a.w};
            float bv[4] = {b.x, b.y, b.z, b.w};
#pragma unroll
            for (int i = 0; i < 4; ++i)
#pragma unroll
                for (int j = 0; j < 4; ++j)
                    acc[i][j] += av[i] * bv[j];
        }
        __syncthreads();
    }

#pragma unroll
    for (int i = 0; i < 4; ++i) {
        int m = m0 + ty * 4 + i;
#pragma unroll
        for (int j = 0; j < 4; ++j) {
            int n = n0 + tx * 4 + j;
            float v = acc[i][j] + bias[n];
            v *= INV_2PI; v = v - floorf(v);
            ph0[(size_t)m * 192 + z * 64 + n] = v;
        }
    }
}

// ============================ Kuramoto (MFMA) ============================
// 16 batch rows/block, 128 blocks. 4 waves; wave w owns osc cols [w*48,w*48+48)
// = 3 tiles of 16. K held in VGPRs as bf16 B-fragments. Per step: sincos ->
// LDS (A-frag layout, parity dbuf) -> 36 MFMAs/wave -> phase update.
__global__ __launch_bounds__(256) void kuramoto_kernel(
    const float* __restrict__ ph_init,   // (B,192) revolutions
    const short* __restrict__ Kp,        // packed bf16 K fragments
    const float* __restrict__ om_eff,    // (192)
    float* __restrict__ phases_out,      // (B,192) radians
    float* __restrict__ pm,              // (B,3) = 0.5+0.5*mean_cos
    float* __restrict__ bacc)            // 3 pair sums
{
    __shared__ alignas(16) short cs[2][2][16][208];  // [parity][c/s][row][osc], stride 208
    __shared__ float Rl[16][3];

    int t = threadIdx.x, lane = t & 63, w = t >> 6;
    int m0 = blockIdx.x * 16;
    int q = lane >> 4, col = lane & 15;

    // K fragments: 18 x bf16x8 = 72 VGPRs, resident for whole kernel
    bf16x8 kb[3][6];
#pragma unroll
    for (int ntl = 0; ntl < 3; ++ntl)
#pragma unroll
        for (int kc = 0; kc < 6; ++kc) {
            int nt = w * 3 + ntl;
            kb[ntl][kc] = *(const bf16x8*)&Kp[((nt * 6 + kc) * 64 + lane) * 8];
        }

    float ph[3][4], om[3], c[3][4], s[3][4];
#pragma unroll
    for (int ntl = 0; ntl < 3; ++ntl) {
        int i = (w * 3 + ntl) * 16 + col;
        om[ntl] = om_eff[i];
#pragma unroll
        for (int r = 0; r < 4; ++r)
            ph[ntl][r] = ph_init[(size_t)(m0 + q * 4 + r) * 192 + i];
    }

    for (int step = 0; step < 10; ++step) {
        int p = step & 1;
#pragma unroll
        for (int ntl = 0; ntl < 3; ++ntl) {
            int i = (w * 3 + ntl) * 16 + col;
#pragma unroll
            for (int r = 0; r < 4; ++r) {
                c[ntl][r] = __builtin_amdgcn_cosf(ph[ntl][r]);  // v_cos_f32: arg in revolutions
                s[ntl][r] = __builtin_amdgcn_sinf(ph[ntl][r]);
                cs[p][0][q * 4 + r][i] = f2bf(c[ntl][r]);
                cs[p][1][q * 4 + r][i] = f2bf(s[ntl][r]);
            }
        }
        __syncthreads();

        f32x4 aC[3], aS[3];
#pragma unroll
        for (int ntl = 0; ntl < 3; ++ntl)
#pragma unroll
            for (int r = 0; r < 4; ++r) { aC[ntl][r] = 0.f; aS[ntl][r] = 0.f; }

#pragma unroll
        for (int kc = 0; kc < 6; ++kc) {
            bf16x8 ac  = *(const bf16x8*)&cs[p][0][col][kc * 32 + q * 8];
            bf16x8 as_ = *(const bf16x8*)&cs[p][1][col][kc * 32 + q * 8];
#pragma unroll
            for (int ntl = 0; ntl < 3; ++ntl) {
                aC[ntl] = __builtin_amdgcn_mfma_f32_16x16x32_bf16(ac,  kb[ntl][kc], aC[ntl], 0, 0, 0);
                aS[ntl] = __builtin_amdgcn_mfma_f32_16x16x32_bf16(as_, kb[ntl][kc], aS[ntl], 0, 0, 0);
            }
        }

#pragma unroll
        for (int ntl = 0; ntl < 3; ++ntl)
#pragma unroll
            for (int r = 0; r < 4; ++r) {
                float f = (s[ntl][r] * aC[ntl][r] - c[ntl][r] * aS[ntl][r]) * FSCALE;
                float pn = ph[ntl][r] + om[ntl] + f;
                ph[ntl][r] = pn - floorf(pn);
            }
    }

    // final cos/sin (parity 0; last step read parity 1) + phase output
#pragma unroll
    for (int ntl = 0; ntl < 3; ++ntl) {
        int i = (w * 3 + ntl) * 16 + col;
#pragma unroll
        for (int r = 0; r < 4; ++r) {
            float cp = __builtin_amdgcn_cosf(ph[ntl][r]);
            float sp = __builtin_amdgcn_sinf(ph[ntl][r]);
            cs[0][0][q * 4 + r][i] = f2bf(cp);
            cs[0][1][q * 4 + r][i] = f2bf(sp);
            phases_out[(size_t)(m0 + q * 4 + r) * 192 + i] = ph[ntl][r] * TWO_PI_F;
        }
    }
    __syncthreads();

    if (t < 48) {
        int r = t & 15, mod = t >> 4;
        float sc = 0.f, ss = 0.f;
#pragma unroll
        for (int g = 0; g < 8; ++g) {
            bf16x8 vc = *(const bf16x8*)&cs[0][0][r][mod * 64 + g * 8];
            bf16x8 vs = *(const bf16x8*)&cs[0][1][r][mod * 64 + g * 8];
#pragma unroll
            for (int j = 0; j < 8; ++j) { sc += bf2f(vc[j]); ss += bf2f(vs[j]); }
        }
        sc *= (1.f / 64.f); ss *= (1.f / 64.f);
        pm[(size_t)(m0 + r) * 3 + mod] = 0.5f + 0.5f * sc;
        Rl[r][mod] = sqrtf(sc * sc + ss * ss);
    }
    __syncthreads();
    if (t < 3) {
        int a = (t == 2) ? 1 : 0;
        int b = (t == 0) ? 1 : 2;
        float accp = 0.f;
        for (int r = 0; r < 16; ++r) accp += Rl[r][a] * Rl[r][b];
        atomicAdd(&bacc[t], accp);
    }
}

// ============================ fusion GEMM (bf16 MFMA) ============================
// bound = (e * pm_scale) @ W_fusion^T + b_fusion. A = e_bf16 scaled per-row/modality.
__global__ __launch_bounds__(256) void fusion_gemm_kernel(
    const short* __restrict__ e_bf16, const short* __restrict__ Wbfu,
    const float* __restrict__ bias, const float* __restrict__ pm,
    float* __restrict__ out)
{
    int m0 = blockIdx.x * 128, n0 = blockIdx.y * 128;
    int t = threadIdx.x;
    int lane = t & 63, w = t >> 6;
    int wm = w >> 1, wn = w & 1;
    int q = lane >> 4, col = lane & 15;

    __shared__ alignas(16) short As[128][32];
    __shared__ alignas(16) short Bs[128][32];

    f32x4 acc[4][4];
#pragma unroll
    for (int i = 0; i < 4; ++i)
#pragma unroll
        for (int j = 0; j < 4; ++j)
#pragma unroll
            for (int r = 0; r < 4; ++r) acc[i][j][r] = 0.f;

    for (int k0 = 0; k0 < 768; k0 += 32) {
        int mod = k0 >> 8;   // 32-chunk never straddles a 256 boundary
#pragma unroll
        for (int p = 0; p < 2; ++p) {
            int idx = t + 256 * p;
            int row = idx >> 2, c8 = idx & 3;
            bf16x8 v = *(const bf16x8*)&e_bf16[(size_t)(m0 + row) * 768 + k0 + c8 * 8];
            float sc = pm[(size_t)(m0 + row) * 3 + mod];
            bf16x8 h;
#pragma unroll
            for (int j = 0; j < 8; ++j) h[j] = f2bf(bf2f(v[j]) * sc);
            *(bf16x8*)&As[row][c8 * 8] = h;
        }
#pragma unroll
        for (int p = 0; p < 2; ++p) {
            int idx = t + 256 * p;
            int row = idx >> 2, c8 = idx & 3;
            *(bf16x8*)&Bs[row][c8 * 8] = *(const bf16x8*)&Wbfu[(size_t)(n0 + row) * 768 + k0 + c8 * 8];
        }
        __syncthreads();

        bf16x8 af[4], bf[4];
#pragma unroll
        for (int f = 0; f < 4; ++f) {
            af[f] = *(const bf16x8*)&As[wm * 64 + f * 16 + col][q * 8];
            bf[f] = *(const bf16x8*)&Bs[wn * 64 + f * 16 + col][q * 8];
        }
#pragma unroll
        for (int fm = 0; fm < 4; ++fm)
#pragma unroll
            for (int fn = 0; fn < 4; ++fn)
                acc[fm][fn] = __builtin_amdgcn_mfma_f32_16x16x32_bf16(af[fm], bf[fn], acc[fm][fn], 0, 0, 0);
        __syncthreads();
    }

#pragma unroll
    for (int fn = 0; fn < 4; ++fn) {
        int n = n0 + wn * 64 + fn * 16 + col;
        float bn = bias[n];
#pragma unroll
        for (int fm = 0; fm < 4; ++fm)
#pragma unroll
            for (int r = 0; r < 4; ++r) {
                int m = m0 + wm * 64 + fm * 16 + q * 4 + r;
                out[(size_t)m * 256 + n] = acc[fm][fn][r] + bn;
            }
    }
}

// ============================ finalize ============================
__global__ __launch_bounds__(256) void finalize_kernel(
    const float* __restrict__ bacc, float* __restrict__ out_bm, float* __restrict__ out_total)
{
    float p01 = bacc[0] * (1.f / 2048.f);
    float p02 = bacc[1] * (1.f / 2048.f);
    float p12 = bacc[2] * (1.f / 2048.f);
    float total = (p01 + p02 + p12) * (1.f / 3.f);
    int t = threadIdx.x;
    if (t == 0) {
        out_bm[0] = 1.f; out_bm[1] = p01; out_bm[2] = p02;
        out_bm[3] = p01; out_bm[4] = 1.f; out_bm[5] = p12;
        out_bm[6] = p02; out_bm[7] = p12; out_bm[8] = 1.f;
    }
    for (int i = t; i < 2048; i += 256) out_total[i] = total;
}

// ============================ launch ============================
extern "C" void kernel_launch(void* const* d_in, const int* in_sizes, int n_in,
                              void* d_out, int out_size, void* d_ws, size_t ws_size,
                              hipStream_t stream)
{
    const float* x_a  = (const float*)d_in[0];
    const float* Wf_a = (const float*)d_in[1];
    const float* bf_a = (const float*)d_in[2];
    const float* Wp_a = (const float*)d_in[3];
    const float* bp_a = (const float*)d_in[4];
    const float* x_t  = (const float*)d_in[5];
    const float* Wf_t = (const float*)d_in[6];
    const float* bf_t = (const float*)d_in[7];
    const float* Wp_t = (const float*)d_in[8];
    const float* bp_t = (const float*)d_in[9];
    const float* x_v  = (const float*)d_in[10];
    const float* Wf_v = (const float*)d_in[11];
    const float* bf_v = (const float*)d_in[12];
    const float* Wp_v = (const float*)d_in[13];
    const float* bp_v = (const float*)d_in[14];
    const float* om_a = (const float*)d_in[15];
    const float* om_t = (const float*)d_in[16];
    const float* om_v = (const float*)d_in[17];
    const float* IC   = (const float*)d_in[18];
    const float* Wfu  = (const float*)d_in[19];
    const float* bfu  = (const float*)d_in[20];

    float* ws    = (float*)d_ws;
    float* ph0   = ws;                 // 393216 f
    float* omw   = ws + 393216;        // 256 f
    float* pmv   = ws + 393472;        // 6144 f
    float* baccw = ws + 399616;        // 64 f
    short* e_bf  = (short*)(ws + 399680);   // 2048*768 = 1572864 shorts
    short* Wbf   = e_bf + 1572864;          // 786432 shorts
    short* Kpck  = Wbf + 786432;            // 36864 shorts

    float* out        = (float*)d_out;
    float* out_bound  = out;           // 2048*256
    float* out_bm     = out + 524288;  // 9
    float* out_phases = out + 524297;  // 2048*192
    float* out_total  = out + 917513;  // 2048

    prep_kernel<<<256, 256, 0, stream>>>(IC, om_a, om_t, om_v,
                                         Wf_a, Wf_t, Wf_v, Wfu,
                                         Wbf, Kpck, omw, baccw);

    dim3 gE(16, 2, 3);
    encode_gemm_kernel<<<gE, 256, 0, stream>>>(x_a, x_t, x_v, Wbf,
                                               bf_a, bf_t, bf_v, e_bf);

    dim3 gP(32, 1, 3);
    phase_gemm_kernel<<<gP, 256, 0, stream>>>(x_a, x_t, x_v,
                                              Wp_a, Wp_t, Wp_v,
                                              bp_a, bp_t, bp_v, ph0);

    kuramoto_kernel<<<128, 256, 0, stream>>>(ph0, Kpck, omw, out_phases, pmv, baccw);

    finalize_kernel<<<1, 256, 0, stream>>>(baccw, out_bm, out_total);

    dim3 gF(16, 2);
    fusion_gemm_kernel<<<gF, 256, 0, stream>>>(e_bf, Wbf + 589824, bfu, pmv, out_bound);
}

// Round 3
// 212.057 us; speedup vs baseline: 2.5302x; 1.1069x over previous
//
#include <hip/hip_runtime.h>
#include <math.h>

typedef short bf16x8 __attribute__((ext_vector_type(8)));
typedef short bf16x4 __attribute__((ext_vector_type(4)));
typedef float f32x4  __attribute__((ext_vector_type(4)));

#define INV_2PI  0.15915494309189535f
#define TWO_PI_F 6.283185307179586f
// DT/(2*pi)/N = 0.01/(2*pi)/192
#define FSCALE   8.2893199e-06f

static __device__ inline short f2bf(float f) {
    union { float f; unsigned u; } v; v.f = f;
    unsigned r = (v.u + 0x7FFFu + ((v.u >> 16) & 1u)) >> 16;
    return (short)r;
}
static __device__ inline float bf2f(short h) {
    union { unsigned u; float f; } v; v.u = ((unsigned)(unsigned short)h) << 16;
    return v.f;
}

// ============================ prep ============================
// Wb = bf16(Wf_a|Wf_t|Wf_v|W_fusion); Kp = bf16 Ksym in 16x16x32 B-frag layout;
// om_eff = omega*DT/2pi; bp_all = concat biases; bacc zeroed.
__global__ __launch_bounds__(256) void prep_kernel(
    const float* __restrict__ IC,
    const float* __restrict__ oa, const float* __restrict__ ot, const float* __restrict__ ov,
    const float* __restrict__ bpa, const float* __restrict__ bpt, const float* __restrict__ bpv,
    const float* __restrict__ Wf_a, const float* __restrict__ Wf_t,
    const float* __restrict__ Wf_v, const float* __restrict__ Wfu,
    short* __restrict__ Wb, short* __restrict__ Kp,
    float* __restrict__ om_eff, float* __restrict__ bp_all, float* __restrict__ bacc)
{
    int t = blockIdx.x * 256 + threadIdx.x;
    int nthr = gridDim.x * 256;
    for (int idx = t; idx < 786432; idx += nthr) {
        float v;
        if (idx < 131072)       v = Wf_a[idx];
        else if (idx < 327680)  v = Wf_t[idx - 131072];
        else if (idx < 589824)  v = Wf_v[idx - 327680];
        else                    v = Wfu[idx - 589824];
        Wb[idx] = f2bf(v);
    }
    // B-frag layout 16x16x32: lane holds B[k=kc*32+(lane>>4)*8+j][n=nt*16+(lane&15)]
    for (int idx = t; idx < 36864; idx += nthr) {
        int k = idx / 192, n = idx - k * 192;
        float v = 0.5f * (IC[k * 192 + n] + IC[n * 192 + k]);
        int nt = n >> 4, kc = k >> 5;
        int lane = ((k >> 3) & 3) * 16 + (n & 15);
        int j = k & 7;
        Kp[((nt * 6 + kc) * 64 + lane) * 8 + j] = f2bf(v);
    }
    if (blockIdx.x == 0) {
        int tt = threadIdx.x;
        if (tt < 192) {
            float w = tt < 64 ? oa[tt] : (tt < 128 ? ot[tt - 64] : ov[tt - 128]);
            om_eff[tt] = w * (0.01f * INV_2PI);
            float b = tt < 64 ? bpa[tt] : (tt < 128 ? bpt[tt - 64] : bpv[tt - 128]);
            bp_all[tt] = b;
        }
        if (tt < 4) bacc[tt] = 0.f;
    }
}

// ============================ phase partial GEMM (fp32, split-K) ============================
// slot -> (z, k-chunk of 256). Block: 32 rows x 64 cols x 256 K, fp32 partial out.
// grid (64, 9) = 576 blocks. Phase math stays fp32 (mod-2pi wrap safety).
__global__ __launch_bounds__(256) void phase_partial_kernel(
    const float* __restrict__ xa, const float* __restrict__ xt, const float* __restrict__ xv,
    const float* __restrict__ Wpa, const float* __restrict__ Wpt, const float* __restrict__ Wpv,
    float* __restrict__ partial)
{
    int slot = blockIdx.y;
    int z = slot < 2 ? 0 : (slot < 5 ? 1 : 2);
    int chunk = slot - (z == 0 ? 0 : (z == 1 ? 2 : 5));
    const float* A = z == 0 ? xa : (z == 1 ? xt : xv);
    const float* W = z == 0 ? Wpa : (z == 1 ? Wpt : Wpv);
    int K = z == 0 ? 512 : (z == 1 ? 768 : 1024);
    int kb = chunk * 256;
    int m0 = blockIdx.x * 32;

    int t = threadIdx.x;
    int tx = t & 15, ty = t >> 4;
    int lk = t & 15, lm = t >> 4;

    __shared__ float As[16][34];   // 34: even pad -> 8B-aligned float2 rows, conflict-free
    __shared__ float Bs[16][68];

    float acc[2][4] = {};

    for (int k0 = 0; k0 < 256; k0 += 16) {
        As[lk][lm]      = A[(size_t)(m0 + lm) * K + kb + k0 + lk];
        As[lk][lm + 16] = A[(size_t)(m0 + lm + 16) * K + kb + k0 + lk];
#pragma unroll
        for (int j = 0; j < 4; ++j)
            Bs[lk][lm + 16 * j] = W[(size_t)(lm + 16 * j) * K + kb + k0 + lk];
        __syncthreads();
#pragma unroll
        for (int kk = 0; kk < 16; ++kk) {
            float2 a = *(const float2*)&As[kk][ty * 2];
            float4 b = *(const float4*)&Bs[kk][tx * 4];
            float av[2] = {a.x, a.y};
            float bv[4] = {b.x, b.y, b.z, b.w};
#pragma unroll
            for (int i = 0; i < 2; ++i)
#pragma unroll
                for (int j = 0; j < 4; ++j)
                    acc[i][j] += av[i] * bv[j];
        }
        __syncthreads();
    }

    float* P = partial + (size_t)slot * 131072;
#pragma unroll
    for (int i = 0; i < 2; ++i) {
        float4 v = make_float4(acc[i][0], acc[i][1], acc[i][2], acc[i][3]);
        *(float4*)&P[(size_t)(m0 + ty * 2 + i) * 64 + tx * 4] = v;
    }
}

// ============================ encode GEMM (bf16 MFMA) ============================
// e_bf16[m][z*256+n] = bf16(x_z @ Wf_z^T + bf_z). BM=BN=64, BK=64, grid (32,4,3)=384.
// 4 waves; wave w owns 16 output cols. Pad 72 shorts -> 2-way (free) frag reads.
__global__ __launch_bounds__(256) void encode_gemm_kernel(
    const float* __restrict__ xa, const float* __restrict__ xt, const float* __restrict__ xv,
    const short* __restrict__ Wb,
    const float* __restrict__ ba, const float* __restrict__ bt, const float* __restrict__ bv,
    short* __restrict__ e_bf16)
{
    int z = blockIdx.z;
    const float* A    = z == 0 ? xa : (z == 1 ? xt : xv);
    const short* W    = z == 0 ? Wb : (z == 1 ? Wb + 131072 : Wb + 327680);
    const float* bias = z == 0 ? ba : (z == 1 ? bt : bv);
    int K             = z == 0 ? 512 : (z == 1 ? 768 : 1024);

    int m0 = blockIdx.x * 64, n0 = blockIdx.y * 64;
    int t = threadIdx.x;
    int lane = t & 63, w = t >> 6;
    int q = lane >> 4, col = lane & 15;

    __shared__ alignas(16) short As[64 * 72];
    __shared__ alignas(16) short Bs[64 * 72];

    f32x4 acc[4];
#pragma unroll
    for (int f = 0; f < 4; ++f)
#pragma unroll
        for (int r = 0; r < 4; ++r) acc[f][r] = 0.f;

    for (int kb = 0; kb < K; kb += 64) {
#pragma unroll
        for (int p = 0; p < 4; ++p) {
            int slot = t + 256 * p;
            int row = slot >> 4, c4 = slot & 15;
            float4 v = *(const float4*)&A[(size_t)(m0 + row) * K + kb + c4 * 4];
            bf16x4 h; h[0] = f2bf(v.x); h[1] = f2bf(v.y); h[2] = f2bf(v.z); h[3] = f2bf(v.w);
            *(bf16x4*)&As[row * 72 + c4 * 4] = h;
        }
#pragma unroll
        for (int p = 0; p < 2; ++p) {
            int slot = t + 256 * p;
            int row = slot >> 3, c8 = slot & 7;
            *(bf16x8*)&Bs[row * 72 + c8 * 8] = *(const bf16x8*)&W[(size_t)(n0 + row) * K + kb + c8 * 8];
        }
        __syncthreads();

        bf16x8 bfr[2];
#pragma unroll
        for (int kc = 0; kc < 2; ++kc)
            bfr[kc] = *(const bf16x8*)&Bs[(w * 16 + col) * 72 + kc * 32 + q * 8];
#pragma unroll
        for (int f = 0; f < 4; ++f)
#pragma unroll
            for (int kc = 0; kc < 2; ++kc) {
                bf16x8 af = *(const bf16x8*)&As[(f * 16 + col) * 72 + kc * 32 + q * 8];
                acc[f] = __builtin_amdgcn_mfma_f32_16x16x32_bf16(af, bfr[kc], acc[f], 0, 0, 0);
            }
        __syncthreads();
    }

    int n = n0 + w * 16 + col;
    float bn = bias[n];
#pragma unroll
    for (int f = 0; f < 4; ++f)
#pragma unroll
        for (int r = 0; r < 4; ++r) {
            int m = m0 + f * 16 + q * 4 + r;
            e_bf16[(size_t)m * 768 + z * 256 + n] = f2bf(acc[f][r] + bn);
        }
}

// ============================ Kuramoto (MFMA) ============================
// Init now folds the split-K phase reduction (+bias, /2pi, fract) inline.
__global__ __launch_bounds__(256) void kuramoto_kernel(
    const float* __restrict__ partial,   // 9 slabs of (2048,64) fp32
    const float* __restrict__ bp_all,    // (192)
    const short* __restrict__ Kp,        // packed bf16 K fragments
    const float* __restrict__ om_eff,    // (192)
    float* __restrict__ phases_out,      // (B,192) radians
    float* __restrict__ pm,              // (B,3) = 0.5+0.5*mean_cos
    float* __restrict__ bacc)            // 3 pair sums
{
    __shared__ alignas(16) short cs[2][2][16][208];
    __shared__ float Rl[16][3];

    int t = threadIdx.x, lane = t & 63, w = t >> 6;
    int m0 = blockIdx.x * 16;
    int q = lane >> 4, col = lane & 15;

    bf16x8 kb[3][6];
#pragma unroll
    for (int ntl = 0; ntl < 3; ++ntl)
#pragma unroll
        for (int kc = 0; kc < 6; ++kc) {
            int nt = w * 3 + ntl;
            kb[ntl][kc] = *(const bf16x8*)&Kp[((nt * 6 + kc) * 64 + lane) * 8];
        }

    float ph[3][4], om[3], c[3][4], s[3][4];
#pragma unroll
    for (int ntl = 0; ntl < 3; ++ntl) {
        int i = (w * 3 + ntl) * 16 + col;
        int z = i >> 6;
        int c0 = (z == 0) ? 0 : (z == 1 ? 2 : 5);
        int nch = z + 2;
        om[ntl] = om_eff[i];
#pragma unroll
        for (int r = 0; r < 4; ++r) {
            float raw = bp_all[i];
#pragma unroll
            for (int cc = 0; cc < 4; ++cc)
                if (cc < nch)
                    raw += partial[(size_t)(c0 + cc) * 131072 + (size_t)(m0 + q * 4 + r) * 64 + (i & 63)];
            raw *= INV_2PI;
            ph[ntl][r] = raw - floorf(raw);
        }
    }

    for (int step = 0; step < 10; ++step) {
        int p = step & 1;
#pragma unroll
        for (int ntl = 0; ntl < 3; ++ntl) {
            int i = (w * 3 + ntl) * 16 + col;
#pragma unroll
            for (int r = 0; r < 4; ++r) {
                c[ntl][r] = __builtin_amdgcn_cosf(ph[ntl][r]);  // v_cos_f32: revolutions
                s[ntl][r] = __builtin_amdgcn_sinf(ph[ntl][r]);
                cs[p][0][q * 4 + r][i] = f2bf(c[ntl][r]);
                cs[p][1][q * 4 + r][i] = f2bf(s[ntl][r]);
            }
        }
        __syncthreads();

        f32x4 aC[3], aS[3];
#pragma unroll
        for (int ntl = 0; ntl < 3; ++ntl)
#pragma unroll
            for (int r = 0; r < 4; ++r) { aC[ntl][r] = 0.f; aS[ntl][r] = 0.f; }

#pragma unroll
        for (int kc = 0; kc < 6; ++kc) {
            bf16x8 ac  = *(const bf16x8*)&cs[p][0][col][kc * 32 + q * 8];
            bf16x8 as_ = *(const bf16x8*)&cs[p][1][col][kc * 32 + q * 8];
#pragma unroll
            for (int ntl = 0; ntl < 3; ++ntl) {
                aC[ntl] = __builtin_amdgcn_mfma_f32_16x16x32_bf16(ac,  kb[ntl][kc], aC[ntl], 0, 0, 0);
                aS[ntl] = __builtin_amdgcn_mfma_f32_16x16x32_bf16(as_, kb[ntl][kc], aS[ntl], 0, 0, 0);
            }
        }

#pragma unroll
        for (int ntl = 0; ntl < 3; ++ntl)
#pragma unroll
            for (int r = 0; r < 4; ++r) {
                float f = (s[ntl][r] * aC[ntl][r] - c[ntl][r] * aS[ntl][r]) * FSCALE;
                float pn = ph[ntl][r] + om[ntl] + f;
                ph[ntl][r] = pn - floorf(pn);
            }
    }

#pragma unroll
    for (int ntl = 0; ntl < 3; ++ntl) {
        int i = (w * 3 + ntl) * 16 + col;
#pragma unroll
        for (int r = 0; r < 4; ++r) {
            float cp = __builtin_amdgcn_cosf(ph[ntl][r]);
            float sp = __builtin_amdgcn_sinf(ph[ntl][r]);
            cs[0][0][q * 4 + r][i] = f2bf(cp);
            cs[0][1][q * 4 + r][i] = f2bf(sp);
            phases_out[(size_t)(m0 + q * 4 + r) * 192 + i] = ph[ntl][r] * TWO_PI_F;
        }
    }
    __syncthreads();

    if (t < 48) {
        int r = t & 15, mod = t >> 4;
        float sc = 0.f, ss = 0.f;
#pragma unroll
        for (int g = 0; g < 8; ++g) {
            bf16x8 vc = *(const bf16x8*)&cs[0][0][r][mod * 64 + g * 8];
            bf16x8 vs = *(const bf16x8*)&cs[0][1][r][mod * 64 + g * 8];
#pragma unroll
            for (int j = 0; j < 8; ++j) { sc += bf2f(vc[j]); ss += bf2f(vs[j]); }
        }
        sc *= (1.f / 64.f); ss *= (1.f / 64.f);
        pm[(size_t)(m0 + r) * 3 + mod] = 0.5f + 0.5f * sc;
        Rl[r][mod] = sqrtf(sc * sc + ss * ss);
    }
    __syncthreads();
    if (t < 3) {
        int a = (t == 2) ? 1 : 0;
        int b = (t == 0) ? 1 : 2;
        float accp = 0.f;
        for (int r = 0; r < 16; ++r) accp += Rl[r][a] * Rl[r][b];
        atomicAdd(&bacc[t], accp);
    }
}

// ============================ fusion GEMM (bf16 MFMA) ============================
// bound = (e * pm_scale) @ W_fusion^T + b_fusion. BM=BN=64, BK=64, grid (32,4)=128.
__global__ __launch_bounds__(256) void fusion_gemm_kernel(
    const short* __restrict__ e_bf16, const short* __restrict__ Wbfu,
    const float* __restrict__ bias, const float* __restrict__ pm,
    float* __restrict__ out)
{
    int m0 = blockIdx.x * 64, n0 = blockIdx.y * 64;
    int t = threadIdx.x;
    int lane = t & 63, w = t >> 6;
    int q = lane >> 4, col = lane & 15;

    __shared__ alignas(16) short As[64 * 72];
    __shared__ alignas(16) short Bs[64 * 72];

    f32x4 acc[4];
#pragma unroll
    for (int f = 0; f < 4; ++f)
#pragma unroll
        for (int r = 0; r < 4; ++r) acc[f][r] = 0.f;

    for (int kb = 0; kb < 768; kb += 64) {
#pragma unroll
        for (int p = 0; p < 2; ++p) {
            int slot = t + 256 * p;
            int row = slot >> 3, c8 = slot & 7;
            int k = kb + c8 * 8;
            int mod = k >> 8;                 // 64-chunks never straddle 256 boundary
            bf16x8 v = *(const bf16x8*)&e_bf16[(size_t)(m0 + row) * 768 + k];
            float sc = pm[(size_t)(m0 + row) * 3 + mod];
            bf16x8 h;
#pragma unroll
            for (int j = 0; j < 8; ++j) h[j] = f2bf(bf2f(v[j]) * sc);
            *(bf16x8*)&As[row * 72 + c8 * 8] = h;

            *(bf16x8*)&Bs[row * 72 + c8 * 8] = *(const bf16x8*)&Wbfu[(size_t)(n0 + row) * 768 + k];
        }
        __syncthreads();

        bf16x8 bfr[2];
#pragma unroll
        for (int kc = 0; kc < 2; ++kc)
            bfr[kc] = *(const bf16x8*)&Bs[(w * 16 + col) * 72 + kc * 32 + q * 8];
#pragma unroll
        for (int f = 0; f < 4; ++f)
#pragma unroll
            for (int kc = 0; kc < 2; ++kc) {
                bf16x8 af = *(const bf16x8*)&As[(f * 16 + col) * 72 + kc * 32 + q * 8];
                acc[f] = __builtin_amdgcn_mfma_f32_16x16x32_bf16(af, bfr[kc], acc[f], 0, 0, 0);
            }
        __syncthreads();
    }

    int n = n0 + w * 16 + col;
    float bn = bias[n];
#pragma unroll
    for (int f = 0; f < 4; ++f)
#pragma unroll
        for (int r = 0; r < 4; ++r) {
            int m = m0 + f * 16 + q * 4 + r;
            out[(size_t)m * 256 + n] = acc[f][r] + bn;
        }
}

// ============================ finalize ============================
__global__ __launch_bounds__(256) void finalize_kernel(
    const float* __restrict__ bacc, float* __restrict__ out_bm, float* __restrict__ out_total)
{
    float p01 = bacc[0] * (1.f / 2048.f);
    float p02 = bacc[1] * (1.f / 2048.f);
    float p12 = bacc[2] * (1.f / 2048.f);
    float total = (p01 + p02 + p12) * (1.f / 3.f);
    int t = threadIdx.x;
    if (t == 0) {
        out_bm[0] = 1.f; out_bm[1] = p01; out_bm[2] = p02;
        out_bm[3] = p01; out_bm[4] = 1.f; out_bm[5] = p12;
        out_bm[6] = p02; out_bm[7] = p12; out_bm[8] = 1.f;
    }
    for (int i = t; i < 2048; i += 256) out_total[i] = total;
}

// ============================ launch ============================
extern "C" void kernel_launch(void* const* d_in, const int* in_sizes, int n_in,
                              void* d_out, int out_size, void* d_ws, size_t ws_size,
                              hipStream_t stream)
{
    const float* x_a  = (const float*)d_in[0];
    const float* Wf_a = (const float*)d_in[1];
    const float* bf_a = (const float*)d_in[2];
    const float* Wp_a = (const float*)d_in[3];
    const float* bp_a = (const float*)d_in[4];
    const float* x_t  = (const float*)d_in[5];
    const float* Wf_t = (const float*)d_in[6];
    const float* bf_t = (const float*)d_in[7];
    const float* Wp_t = (const float*)d_in[8];
    const float* bp_t = (const float*)d_in[9];
    const float* x_v  = (const float*)d_in[10];
    const float* Wf_v = (const float*)d_in[11];
    const float* bf_v = (const float*)d_in[12];
    const float* Wp_v = (const float*)d_in[13];
    const float* bp_v = (const float*)d_in[14];
    const float* om_a = (const float*)d_in[15];
    const float* om_t = (const float*)d_in[16];
    const float* om_v = (const float*)d_in[17];
    const float* IC   = (const float*)d_in[18];
    const float* Wfu  = (const float*)d_in[19];
    const float* bfu  = (const float*)d_in[20];

    float* ws      = (float*)d_ws;
    float* omw     = ws;            // 256
    float* bpw     = ws + 256;      // 256
    float* pmv     = ws + 512;      // 6144
    float* baccw   = ws + 6656;     // 64
    float* partial = ws + 6720;     // 9*131072 = 1179648
    short* e_bf    = (short*)(ws + 1186368);  // 2048*768 shorts
    short* Wbf     = e_bf + 1572864;          // 786432 shorts
    short* Kpck    = Wbf + 786432;            // 36864 shorts

    float* out        = (float*)d_out;
    float* out_bound  = out;           // 2048*256
    float* out_bm     = out + 524288;  // 9
    float* out_phases = out + 524297;  // 2048*192
    float* out_total  = out + 917513;  // 2048

    prep_kernel<<<256, 256, 0, stream>>>(IC, om_a, om_t, om_v,
                                         bp_a, bp_t, bp_v,
                                         Wf_a, Wf_t, Wf_v, Wfu,
                                         Wbf, Kpck, omw, bpw, baccw);

    dim3 gP(64, 9);
    phase_partial_kernel<<<gP, 256, 0, stream>>>(x_a, x_t, x_v,
                                                 Wp_a, Wp_t, Wp_v, partial);

    dim3 gE(32, 4, 3);
    encode_gemm_kernel<<<gE, 256, 0, stream>>>(x_a, x_t, x_v, Wbf,
                                               bf_a, bf_t, bf_v, e_bf);

    kuramoto_kernel<<<128, 256, 0, stream>>>(partial, bpw, Kpck, omw,
                                             out_phases, pmv, baccw);

    finalize_kernel<<<1, 256, 0, stream>>>(baccw, out_bm, out_total);

    dim3 gF(32, 4);
    fusion_gemm_kernel<<<gF, 256, 0, stream>>>(e_bf, Wbf + 589824, bfu, pmv, out_bound);
}

// Round 4
// 204.757 us; speedup vs baseline: 2.6204x; 1.0356x over previous
//
#include <hip/hip_runtime.h>
#include <math.h>

typedef short bf16x8 __attribute__((ext_vector_type(8)));
typedef short bf16x4 __attribute__((ext_vector_type(4)));
typedef float f32x4  __attribute__((ext_vector_type(4)));

#define INV_2PI  0.15915494309189535f
#define TWO_PI_F 6.283185307179586f
// DT/(2*pi)/N = 0.01/(2*pi)/192
#define FSCALE   8.2893199e-06f

static __device__ inline short f2bf(float f) {
    union { float f; unsigned u; } v; v.f = f;
    unsigned r = (v.u + 0x7FFFu + ((v.u >> 16) & 1u)) >> 16;
    return (short)r;
}
static __device__ inline float bf2f(short h) {
    union { unsigned u; float f; } v; v.u = ((unsigned)(unsigned short)h) << 16;
    return v.f;
}

// ============================ K1: front ============================
// blocks [0,576):   phase split-K partial GEMM (fp32, wrap-safe path)
// blocks [576,672): encode GEMM bf16 MFMA, BM=BN=128, BK=64, W converted in staging
// block 672:        Kp pack (bf16 B-frag layout)   block 673: omega/bias/bacc
__global__ __launch_bounds__(256) void front_kernel(
    const float* __restrict__ xa, const float* __restrict__ xt, const float* __restrict__ xv,
    const float* __restrict__ Wpa, const float* __restrict__ Wpt, const float* __restrict__ Wpv,
    const float* __restrict__ Wfa, const float* __restrict__ Wft, const float* __restrict__ Wfv,
    const float* __restrict__ ba, const float* __restrict__ bt, const float* __restrict__ bv,
    const float* __restrict__ IC,
    const float* __restrict__ oa, const float* __restrict__ ot, const float* __restrict__ ov,
    const float* __restrict__ bpa, const float* __restrict__ bpt, const float* __restrict__ bpv,
    float* __restrict__ partial, short* __restrict__ e_bf16, short* __restrict__ Kp,
    float* __restrict__ om_eff, float* __restrict__ bp_all, float* __restrict__ bacc)
{
    __shared__ alignas(16) char smem[2 * 128 * 72 * 2];   // 36864 B (encode view is max)
    int b = blockIdx.x;
    int t = threadIdx.x;

    if (b < 576) {
        // ---------- phase partial: 32 rows x 64 cols x 256 K ----------
        float (*As)[34] = (float (*)[34])smem;                    // 2176 B
        float (*Bs)[68] = (float (*)[68])(smem + 2176);           // 16B-aligned
        int slot = b >> 6;
        int z = slot < 2 ? 0 : (slot < 5 ? 1 : 2);
        int chunk = slot - (z == 0 ? 0 : (z == 1 ? 2 : 5));
        const float* A = z == 0 ? xa : (z == 1 ? xt : xv);
        const float* W = z == 0 ? Wpa : (z == 1 ? Wpt : Wpv);
        int K = z == 0 ? 512 : (z == 1 ? 768 : 1024);
        int kb = chunk * 256;
        int m0 = (b & 63) * 32;

        int tx = t & 15, ty = t >> 4;
        int lk = t & 15, lm = t >> 4;

        float acc[2][4] = {};

        for (int k0 = 0; k0 < 256; k0 += 16) {
            As[lk][lm]      = A[(size_t)(m0 + lm) * K + kb + k0 + lk];
            As[lk][lm + 16] = A[(size_t)(m0 + lm + 16) * K + kb + k0 + lk];
#pragma unroll
            for (int j = 0; j < 4; ++j)
                Bs[lk][lm + 16 * j] = W[(size_t)(lm + 16 * j) * K + kb + k0 + lk];
            __syncthreads();
#pragma unroll
            for (int kk = 0; kk < 16; ++kk) {
                float2 a = *(const float2*)&As[kk][ty * 2];
                float4 bvv = *(const float4*)&Bs[kk][tx * 4];
                float av[2] = {a.x, a.y};
                float bw[4] = {bvv.x, bvv.y, bvv.z, bvv.w};
#pragma unroll
                for (int i = 0; i < 2; ++i)
#pragma unroll
                    for (int j = 0; j < 4; ++j)
                        acc[i][j] += av[i] * bw[j];
            }
            __syncthreads();
        }

        float* P = partial + (size_t)slot * 131072;
#pragma unroll
        for (int i = 0; i < 2; ++i) {
            float4 v = make_float4(acc[i][0], acc[i][1], acc[i][2], acc[i][3]);
            *(float4*)&P[(size_t)(m0 + ty * 2 + i) * 64 + tx * 4] = v;
        }
    } else if (b < 672) {
        // ---------- encode: BM=BN=128, BK=64 ----------
        int e = b - 576;
        int z = e >> 5;
        int r = e & 31;
        int m0 = (r >> 1) * 128, n0 = (r & 1) * 128;
        const float* A    = z == 0 ? xa : (z == 1 ? xt : xv);
        const float* W    = z == 0 ? Wfa : (z == 1 ? Wft : Wfv);
        const float* bias = z == 0 ? ba : (z == 1 ? bt : bv);
        int K             = z == 0 ? 512 : (z == 1 ? 768 : 1024);

        short* As = (short*)smem;              // [128][72]
        short* Bs = (short*)smem + 128 * 72;   // [128][72]

        int lane = t & 63, w = t >> 6;
        int wm = w >> 1, wn = w & 1;
        int q = lane >> 4, col = lane & 15;

        f32x4 acc[4][4];
#pragma unroll
        for (int i = 0; i < 4; ++i)
#pragma unroll
            for (int j = 0; j < 4; ++j)
#pragma unroll
                for (int rr = 0; rr < 4; ++rr) acc[i][j][rr] = 0.f;

        for (int kb = 0; kb < K; kb += 64) {
#pragma unroll
            for (int p = 0; p < 8; ++p) {
                int slot = t + 256 * p;
                int row = slot >> 4, c4 = slot & 15;
                float4 va = *(const float4*)&A[(size_t)(m0 + row) * K + kb + c4 * 4];
                bf16x4 ha; ha[0] = f2bf(va.x); ha[1] = f2bf(va.y); ha[2] = f2bf(va.z); ha[3] = f2bf(va.w);
                *(bf16x4*)&As[row * 72 + c4 * 4] = ha;
                float4 vb = *(const float4*)&W[(size_t)(n0 + row) * K + kb + c4 * 4];
                bf16x4 hb; hb[0] = f2bf(vb.x); hb[1] = f2bf(vb.y); hb[2] = f2bf(vb.z); hb[3] = f2bf(vb.w);
                *(bf16x4*)&Bs[row * 72 + c4 * 4] = hb;
            }
            __syncthreads();
#pragma unroll
            for (int kc = 0; kc < 2; ++kc) {
                bf16x8 af[4], bf[4];
#pragma unroll
                for (int f = 0; f < 4; ++f) {
                    af[f] = *(const bf16x8*)&As[(wm * 64 + f * 16 + col) * 72 + kc * 32 + q * 8];
                    bf[f] = *(const bf16x8*)&Bs[(wn * 64 + f * 16 + col) * 72 + kc * 32 + q * 8];
                }
#pragma unroll
                for (int fm = 0; fm < 4; ++fm)
#pragma unroll
                    for (int fn = 0; fn < 4; ++fn)
                        acc[fm][fn] = __builtin_amdgcn_mfma_f32_16x16x32_bf16(af[fm], bf[fn], acc[fm][fn], 0, 0, 0);
            }
            __syncthreads();
        }

#pragma unroll
        for (int fn = 0; fn < 4; ++fn) {
            int n = n0 + wn * 64 + fn * 16 + col;
            float bn = bias[n];
#pragma unroll
            for (int fm = 0; fm < 4; ++fm)
#pragma unroll
                for (int rr = 0; rr < 4; ++rr) {
                    int m = m0 + wm * 64 + fm * 16 + q * 4 + rr;
                    e_bf16[(size_t)m * 768 + z * 256 + n] = f2bf(acc[fm][fn][rr] + bn);
                }
        }
    } else if (b == 672) {
        // ---------- Kp pack: B-frag 16x16x32 layout ----------
        for (int idx = t; idx < 36864; idx += 256) {
            int k = idx / 192, n = idx - k * 192;
            float v = 0.5f * (IC[k * 192 + n] + IC[n * 192 + k]);
            int nt = n >> 4, kc = k >> 5;
            int lane = ((k >> 3) & 3) * 16 + (n & 15);
            int j = k & 7;
            Kp[((nt * 6 + kc) * 64 + lane) * 8 + j] = f2bf(v);
        }
    } else {
        if (t < 192) {
            float w = t < 64 ? oa[t] : (t < 128 ? ot[t - 64] : ov[t - 128]);
            om_eff[t] = w * (0.01f * INV_2PI);
            float bb = t < 64 ? bpa[t] : (t < 128 ? bpt[t - 64] : bpv[t - 128]);
            bp_all[t] = bb;
        }
        if (t < 4) bacc[t] = 0.f;
    }
}

// ============================ K2: Kuramoto (MFMA) ============================
__global__ __launch_bounds__(256) void kuramoto_kernel(
    const float* __restrict__ partial,   // 9 slabs of (2048,64) fp32
    const float* __restrict__ bp_all,    // (192)
    const short* __restrict__ Kp,        // packed bf16 K fragments
    const float* __restrict__ om_eff,    // (192)
    float* __restrict__ phases_out,      // (B,192) radians
    float* __restrict__ pm,              // (B,3) = 0.5+0.5*mean_cos
    float* __restrict__ bacc)            // 3 pair sums
{
    __shared__ alignas(16) short cs[2][2][16][208];
    __shared__ float Rl[16][3];

    int t = threadIdx.x, lane = t & 63, w = t >> 6;
    int m0 = blockIdx.x * 16;
    int q = lane >> 4, col = lane & 15;

    bf16x8 kb[3][6];
#pragma unroll
    for (int ntl = 0; ntl < 3; ++ntl)
#pragma unroll
        for (int kc = 0; kc < 6; ++kc) {
            int nt = w * 3 + ntl;
            kb[ntl][kc] = *(const bf16x8*)&Kp[((nt * 6 + kc) * 64 + lane) * 8];
        }

    float ph[3][4], om[3], c[3][4], s[3][4];
#pragma unroll
    for (int ntl = 0; ntl < 3; ++ntl) {
        int i = (w * 3 + ntl) * 16 + col;
        int z = i >> 6;
        int c0 = (z == 0) ? 0 : (z == 1 ? 2 : 5);
        int nch = z + 2;
        om[ntl] = om_eff[i];
#pragma unroll
        for (int r = 0; r < 4; ++r) {
            float raw = bp_all[i];
#pragma unroll
            for (int cc = 0; cc < 4; ++cc)
                if (cc < nch)
                    raw += partial[(size_t)(c0 + cc) * 131072 + (size_t)(m0 + q * 4 + r) * 64 + (i & 63)];
            raw *= INV_2PI;
            ph[ntl][r] = raw - floorf(raw);
        }
    }

    for (int step = 0; step < 10; ++step) {
        int p = step & 1;
#pragma unroll
        for (int ntl = 0; ntl < 3; ++ntl) {
            int i = (w * 3 + ntl) * 16 + col;
#pragma unroll
            for (int r = 0; r < 4; ++r) {
                c[ntl][r] = __builtin_amdgcn_cosf(ph[ntl][r]);  // v_cos_f32: revolutions
                s[ntl][r] = __builtin_amdgcn_sinf(ph[ntl][r]);
                cs[p][0][q * 4 + r][i] = f2bf(c[ntl][r]);
                cs[p][1][q * 4 + r][i] = f2bf(s[ntl][r]);
            }
        }
        __syncthreads();

        f32x4 aC[3], aS[3];
#pragma unroll
        for (int ntl = 0; ntl < 3; ++ntl)
#pragma unroll
            for (int r = 0; r < 4; ++r) { aC[ntl][r] = 0.f; aS[ntl][r] = 0.f; }

#pragma unroll
        for (int kc = 0; kc < 6; ++kc) {
            bf16x8 ac  = *(const bf16x8*)&cs[p][0][col][kc * 32 + q * 8];
            bf16x8 as_ = *(const bf16x8*)&cs[p][1][col][kc * 32 + q * 8];
#pragma unroll
            for (int ntl = 0; ntl < 3; ++ntl) {
                aC[ntl] = __builtin_amdgcn_mfma_f32_16x16x32_bf16(ac,  kb[ntl][kc], aC[ntl], 0, 0, 0);
                aS[ntl] = __builtin_amdgcn_mfma_f32_16x16x32_bf16(as_, kb[ntl][kc], aS[ntl], 0, 0, 0);
            }
        }

#pragma unroll
        for (int ntl = 0; ntl < 3; ++ntl)
#pragma unroll
            for (int r = 0; r < 4; ++r) {
                float f = (s[ntl][r] * aC[ntl][r] - c[ntl][r] * aS[ntl][r]) * FSCALE;
                float pn = ph[ntl][r] + om[ntl] + f;
                ph[ntl][r] = pn - floorf(pn);
            }
    }

#pragma unroll
    for (int ntl = 0; ntl < 3; ++ntl) {
        int i = (w * 3 + ntl) * 16 + col;
#pragma unroll
        for (int r = 0; r < 4; ++r) {
            float cp = __builtin_amdgcn_cosf(ph[ntl][r]);
            float sp = __builtin_amdgcn_sinf(ph[ntl][r]);
            cs[0][0][q * 4 + r][i] = f2bf(cp);
            cs[0][1][q * 4 + r][i] = f2bf(sp);
            phases_out[(size_t)(m0 + q * 4 + r) * 192 + i] = ph[ntl][r] * TWO_PI_F;
        }
    }
    __syncthreads();

    if (t < 48) {
        int r = t & 15, mod = t >> 4;
        float sc = 0.f, ss = 0.f;
#pragma unroll
        for (int g = 0; g < 8; ++g) {
            bf16x8 vc = *(const bf16x8*)&cs[0][0][r][mod * 64 + g * 8];
            bf16x8 vs = *(const bf16x8*)&cs[0][1][r][mod * 64 + g * 8];
#pragma unroll
            for (int j = 0; j < 8; ++j) { sc += bf2f(vc[j]); ss += bf2f(vs[j]); }
        }
        sc *= (1.f / 64.f); ss *= (1.f / 64.f);
        pm[(size_t)(m0 + r) * 3 + mod] = 0.5f + 0.5f * sc;
        Rl[r][mod] = sqrtf(sc * sc + ss * ss);
    }
    __syncthreads();
    if (t < 3) {
        int a = (t == 2) ? 1 : 0;
        int bidx = (t == 0) ? 1 : 2;
        float accp = 0.f;
        for (int r = 0; r < 16; ++r) accp += Rl[r][a] * Rl[r][bidx];
        atomicAdd(&bacc[t], accp);
    }
}

// ============================ K3: fusion + finalize ============================
// bound = (e * pm_scale) @ W_fusion^T + b_fusion; Wfu converted fp32->bf16 in staging.
// Block (0,0) also emits binding_matrix + total_binding (bacc ready: K2 precedes).
__global__ __launch_bounds__(256) void back_kernel(
    const short* __restrict__ e_bf16, const float* __restrict__ Wfu,
    const float* __restrict__ bias, const float* __restrict__ pm,
    const float* __restrict__ bacc,
    float* __restrict__ out_bound, float* __restrict__ out_bm, float* __restrict__ out_total)
{
    int m0 = blockIdx.x * 64, n0 = blockIdx.y * 64;
    int t = threadIdx.x;
    int lane = t & 63, w = t >> 6;
    int q = lane >> 4, col = lane & 15;

    __shared__ alignas(16) short As[64 * 72];
    __shared__ alignas(16) short Bs[64 * 72];

    f32x4 acc[4];
#pragma unroll
    for (int f = 0; f < 4; ++f)
#pragma unroll
        for (int r = 0; r < 4; ++r) acc[f][r] = 0.f;

    for (int kb = 0; kb < 768; kb += 64) {
#pragma unroll
        for (int p = 0; p < 2; ++p) {
            int slot = t + 256 * p;
            int row = slot >> 3, c8 = slot & 7;
            int k = kb + c8 * 8;
            int mod = k >> 8;
            bf16x8 v = *(const bf16x8*)&e_bf16[(size_t)(m0 + row) * 768 + k];
            float sc = pm[(size_t)(m0 + row) * 3 + mod];
            bf16x8 h;
#pragma unroll
            for (int j = 0; j < 8; ++j) h[j] = f2bf(bf2f(v[j]) * sc);
            *(bf16x8*)&As[row * 72 + c8 * 8] = h;
        }
#pragma unroll
        for (int p = 0; p < 4; ++p) {
            int slot = t + 256 * p;
            int row = slot >> 4, c4 = slot & 15;
            float4 vb = *(const float4*)&Wfu[(size_t)(n0 + row) * 768 + kb + c4 * 4];
            bf16x4 hb; hb[0] = f2bf(vb.x); hb[1] = f2bf(vb.y); hb[2] = f2bf(vb.z); hb[3] = f2bf(vb.w);
            *(bf16x4*)&Bs[row * 72 + c4 * 4] = hb;
        }
        __syncthreads();

        bf16x8 bfr[2];
#pragma unroll
        for (int kc = 0; kc < 2; ++kc)
            bfr[kc] = *(const bf16x8*)&Bs[(w * 16 + col) * 72 + kc * 32 + q * 8];
#pragma unroll
        for (int f = 0; f < 4; ++f)
#pragma unroll
            for (int kc = 0; kc < 2; ++kc) {
                bf16x8 af = *(const bf16x8*)&As[(f * 16 + col) * 72 + kc * 32 + q * 8];
                acc[f] = __builtin_amdgcn_mfma_f32_16x16x32_bf16(af, bfr[kc], acc[f], 0, 0, 0);
            }
        __syncthreads();
    }

    int n = n0 + w * 16 + col;
    float bn = bias[n];
#pragma unroll
    for (int f = 0; f < 4; ++f)
#pragma unroll
        for (int r = 0; r < 4; ++r) {
            int m = m0 + f * 16 + q * 4 + r;
            out_bound[(size_t)m * 256 + n] = acc[f][r] + bn;
        }

    if (blockIdx.x == 0 && blockIdx.y == 0) {
        float p01 = bacc[0] * (1.f / 2048.f);
        float p02 = bacc[1] * (1.f / 2048.f);
        float p12 = bacc[2] * (1.f / 2048.f);
        float total = (p01 + p02 + p12) * (1.f / 3.f);
        if (t == 0) {
            out_bm[0] = 1.f; out_bm[1] = p01; out_bm[2] = p02;
            out_bm[3] = p01; out_bm[4] = 1.f; out_bm[5] = p12;
            out_bm[6] = p02; out_bm[7] = p12; out_bm[8] = 1.f;
        }
        for (int i = t; i < 2048; i += 256) out_total[i] = total;
    }
}

// ============================ launch ============================
extern "C" void kernel_launch(void* const* d_in, const int* in_sizes, int n_in,
                              void* d_out, int out_size, void* d_ws, size_t ws_size,
                              hipStream_t stream)
{
    const float* x_a  = (const float*)d_in[0];
    const float* Wf_a = (const float*)d_in[1];
    const float* bf_a = (const float*)d_in[2];
    const float* Wp_a = (const float*)d_in[3];
    const float* bp_a = (const float*)d_in[4];
    const float* x_t  = (const float*)d_in[5];
    const float* Wf_t = (const float*)d_in[6];
    const float* bf_t = (const float*)d_in[7];
    const float* Wp_t = (const float*)d_in[8];
    const float* bp_t = (const float*)d_in[9];
    const float* x_v  = (const float*)d_in[10];
    const float* Wf_v = (const float*)d_in[11];
    const float* bf_v = (const float*)d_in[12];
    const float* Wp_v = (const float*)d_in[13];
    const float* bp_v = (const float*)d_in[14];
    const float* om_a = (const float*)d_in[15];
    const float* om_t = (const float*)d_in[16];
    const float* om_v = (const float*)d_in[17];
    const float* IC   = (const float*)d_in[18];
    const float* Wfu  = (const float*)d_in[19];
    const float* bfu  = (const float*)d_in[20];

    float* ws      = (float*)d_ws;
    float* omw     = ws;            // 256
    float* bpw     = ws + 256;      // 256
    float* pmv     = ws + 512;      // 6144
    float* baccw   = ws + 6656;     // 64
    float* partial = ws + 6720;     // 9*131072
    short* e_bf    = (short*)(ws + 1186368);  // 2048*768 shorts
    short* Kpck    = e_bf + 1572864;          // 36864 shorts

    float* out        = (float*)d_out;
    float* out_bound  = out;           // 2048*256
    float* out_bm     = out + 524288;  // 9
    float* out_phases = out + 524297;  // 2048*192
    float* out_total  = out + 917513;  // 2048

    front_kernel<<<674, 256, 0, stream>>>(
        x_a, x_t, x_v, Wp_a, Wp_t, Wp_v, Wf_a, Wf_t, Wf_v,
        bf_a, bf_t, bf_v, IC, om_a, om_t, om_v, bp_a, bp_t, bp_v,
        partial, e_bf, Kpck, omw, bpw, baccw);

    kuramoto_kernel<<<128, 256, 0, stream>>>(partial, bpw, Kpck, omw,
                                             out_phases, pmv, baccw);

    dim3 gF(32, 4);
    back_kernel<<<gF, 256, 0, stream>>>(e_bf, Wfu, bfu, pmv, baccw,
                                        out_bound, out_bm, out_total);
}

// Round 5
// 176.755 us; speedup vs baseline: 3.0355x; 1.1584x over previous
//
#include <hip/hip_runtime.h>
#include <math.h>

typedef short bf16x8 __attribute__((ext_vector_type(8)));
typedef short bf16x4 __attribute__((ext_vector_type(4)));
typedef float f32x4  __attribute__((ext_vector_type(4)));

#define INV_2PI  0.15915494309189535f
#define TWO_PI_F 6.283185307179586f
// DT/(2*pi)/N = 0.01/(2*pi)/192
#define FSCALE   8.2893199e-06f

static __device__ inline short f2bf(float f) {
    union { float f; unsigned u; } v; v.f = f;
    unsigned r = (v.u + 0x7FFFu + ((v.u >> 16) & 1u)) >> 16;
    return (short)r;
}
static __device__ inline float bf2f(short h) {
    union { unsigned u; float f; } v; v.u = ((unsigned)(unsigned short)h) << 16;
    return v.f;
}

// ============================ K1: front ============================
// [0,288):   phase split-K partials, fp32, 128 rows x 64 cols x 128-K chunk
//            (18 slots x 16 row-blocks), 8x4 micro-tile (FMA-bound)
// [288,372): fp32->bf16 convert of x (3) and W (4) into XB/WB concat
// [372,404): Kp pack (bf16 B-frag layout), parallel
// 404:       omega/bias/bacc
__global__ __launch_bounds__(256) void front_kernel(
    const float* __restrict__ xa, const float* __restrict__ xt, const float* __restrict__ xv,
    const float* __restrict__ Wpa, const float* __restrict__ Wpt, const float* __restrict__ Wpv,
    const float* __restrict__ Wfa, const float* __restrict__ Wft, const float* __restrict__ Wfv,
    const float* __restrict__ Wfu,
    const float* __restrict__ IC,
    const float* __restrict__ oa, const float* __restrict__ ot, const float* __restrict__ ov,
    const float* __restrict__ bpa, const float* __restrict__ bpt, const float* __restrict__ bpv,
    float* __restrict__ partial, short* __restrict__ XB, short* __restrict__ WB,
    short* __restrict__ Kp,
    float* __restrict__ om_eff, float* __restrict__ bp_all, float* __restrict__ bacc)
{
    __shared__ alignas(16) char smem[13056];
    int b = blockIdx.x;
    int t = threadIdx.x;

    if (b < 288) {
        // ---------- phase partial ----------
        float (*As)[136] = (float (*)[136])smem;            // 8704 B
        float (*Bs)[68]  = (float (*)[68])(smem + 8704);    // 4352 B
        int slot = b % 18, rb = b / 18;
        int z = slot < 4 ? 0 : (slot < 10 ? 1 : 2);
        int chunk = slot - (z == 0 ? 0 : (z == 1 ? 4 : 10));
        const float* A = z == 0 ? xa : (z == 1 ? xt : xv);
        const float* W = z == 0 ? Wpa : (z == 1 ? Wpt : Wpv);
        int K = z == 0 ? 512 : (z == 1 ? 768 : 1024);
        int kb = chunk * 128;
        int m0 = rb * 128;

        int tx = t & 15, ty = t >> 4;
        int c4 = t & 3, lr = t >> 2;    // staging: f4 col group, row

        float acc[8][4] = {};

        for (int k0 = 0; k0 < 128; k0 += 16) {
            // A: 128 rows x 16 k, f4 loads, transpose into As[k][row]
#pragma unroll
            for (int h = 0; h < 2; ++h) {
                int row = lr + 64 * h;
                float4 v = *(const float4*)&A[(size_t)(m0 + row) * K + kb + k0 + c4 * 4];
                As[c4 * 4 + 0][row] = v.x;
                As[c4 * 4 + 1][row] = v.y;
                As[c4 * 4 + 2][row] = v.z;
                As[c4 * 4 + 3][row] = v.w;
            }
            // B: 64 rows x 16 k
            {
                int row = lr & 63;
                if (t < 256) {
                    float4 v = *(const float4*)&W[(size_t)row * K + kb + k0 + c4 * 4];
                    if (lr < 64) {
                        Bs[c4 * 4 + 0][row] = v.x;
                        Bs[c4 * 4 + 1][row] = v.y;
                        Bs[c4 * 4 + 2][row] = v.z;
                        Bs[c4 * 4 + 3][row] = v.w;
                    }
                }
            }
            __syncthreads();
#pragma unroll
            for (int kk = 0; kk < 16; ++kk) {
                float4 a0 = *(const float4*)&As[kk][ty * 8];
                float4 a1 = *(const float4*)&As[kk][ty * 8 + 4];
                float4 bq = *(const float4*)&Bs[kk][tx * 4];
                float av[8] = {a0.x, a0.y, a0.z, a0.w, a1.x, a1.y, a1.z, a1.w};
                float bv[4] = {bq.x, bq.y, bq.z, bq.w};
#pragma unroll
                for (int i = 0; i < 8; ++i)
#pragma unroll
                    for (int j = 0; j < 4; ++j)
                        acc[i][j] += av[i] * bv[j];
            }
            __syncthreads();
        }

        float* P = partial + (size_t)slot * 131072;
#pragma unroll
        for (int i = 0; i < 8; ++i) {
            float4 v = make_float4(acc[i][0], acc[i][1], acc[i][2], acc[i][3]);
            *(float4*)&P[(size_t)(m0 + ty * 8 + i) * 64 + tx * 4] = v;
        }
    } else if (b < 372) {
        // ---------- convert fp32 -> bf16 (f4 units) ----------
        // prefix (f4 units): xa 262144 | xt 655360 | xv 1179648 |
        //                    Wfa 1212416 | Wft 1261568 | Wfv 1327104 | Wfu 1376256
        for (int u = (b - 288) * 256 + t; u < 1376256; u += 84 * 256) {
            const float4* sp; short* dp;
            if (u < 262144)       { sp = (const float4*)xa  + u;            dp = XB + (size_t)u * 4; }
            else if (u < 655360)  { sp = (const float4*)xt  + (u - 262144); dp = XB + (size_t)u * 4; }
            else if (u < 1179648) { sp = (const float4*)xv  + (u - 655360); dp = XB + (size_t)u * 4; }
            else if (u < 1212416) { sp = (const float4*)Wfa + (u - 1179648); dp = WB + (size_t)(u - 1179648) * 4; }
            else if (u < 1261568) { sp = (const float4*)Wft + (u - 1212416); dp = WB + (size_t)(u - 1179648) * 4; }
            else if (u < 1327104) { sp = (const float4*)Wfv + (u - 1261568); dp = WB + (size_t)(u - 1179648) * 4; }
            else                  { sp = (const float4*)Wfu + (u - 1327104); dp = WB + (size_t)(u - 1179648) * 4; }
            float4 v = *sp;
            bf16x4 h; h[0] = f2bf(v.x); h[1] = f2bf(v.y); h[2] = f2bf(v.z); h[3] = f2bf(v.w);
            *(bf16x4*)dp = h;
        }
    } else if (b < 404) {
        // ---------- Kp pack: B-frag 16x16x32 layout (parallel) ----------
        for (int idx = (b - 372) * 256 + t; idx < 36864; idx += 32 * 256) {
            int k = idx / 192, n = idx - k * 192;
            float v = 0.5f * (IC[k * 192 + n] + IC[n * 192 + k]);
            int nt = n >> 4, kc = k >> 5;
            int lane = ((k >> 3) & 3) * 16 + (n & 15);
            int j = k & 7;
            Kp[((nt * 6 + kc) * 64 + lane) * 8 + j] = f2bf(v);
        }
    } else {
        if (t < 192) {
            float w = t < 64 ? oa[t] : (t < 128 ? ot[t - 64] : ov[t - 128]);
            om_eff[t] = w * (0.01f * INV_2PI);
            float bb = t < 64 ? bpa[t] : (t < 128 ? bpt[t - 64] : bpv[t - 128]);
            bp_all[t] = bb;
        }
        if (t < 4) bacc[t] = 0.f;
    }
}

// ============================ K2: encode + kuramoto ============================
// [0,384):   encode GEMM bf16 MFMA, 64x64 tile, BK=64, bf16 pre-converted inputs
// [384,512): kuramoto (16 rows/block), folds split-K phase reduction at init
__global__ __launch_bounds__(256) void mid_kernel(
    const short* __restrict__ XB, const short* __restrict__ WB,
    const float* __restrict__ ba, const float* __restrict__ bt, const float* __restrict__ bv,
    const float* __restrict__ partial, const float* __restrict__ bp_all,
    const short* __restrict__ Kp, const float* __restrict__ om_eff,
    short* __restrict__ e_bf16,
    float* __restrict__ phases_out, float* __restrict__ pm, float* __restrict__ bacc)
{
    __shared__ alignas(16) char smem[26816];
    int b = blockIdx.x;
    int t = threadIdx.x;
    int lane = t & 63, w = t >> 6;
    int q = lane >> 4, col = lane & 15;

    if (b < 384) {
        // ---------- encode ----------
        int z = b / 128, r = b % 128;
        int m0 = (r >> 2) * 64, n0 = (r & 3) * 64;
        const short* A    = XB + (z == 0 ? 0 : (z == 1 ? 1048576 : 2621440));
        const short* W    = WB + (z == 0 ? 0 : (z == 1 ? 131072 : 327680));
        const float* bias = z == 0 ? ba : (z == 1 ? bt : bv);
        int K             = z == 0 ? 512 : (z == 1 ? 768 : 1024);

        short* As = (short*)smem;            // [64][72]
        short* Bs = (short*)smem + 64 * 72;

        f32x4 acc[4];
#pragma unroll
        for (int f = 0; f < 4; ++f)
#pragma unroll
            for (int rr = 0; rr < 4; ++rr) acc[f][rr] = 0.f;

        for (int kb = 0; kb < K; kb += 64) {
#pragma unroll
            for (int p = 0; p < 2; ++p) {
                int u = t + 256 * p;
                int row = u >> 3, c8 = u & 7;
                *(bf16x8*)&As[row * 72 + c8 * 8] = *(const bf16x8*)&A[(size_t)(m0 + row) * K + kb + c8 * 8];
                *(bf16x8*)&Bs[row * 72 + c8 * 8] = *(const bf16x8*)&W[(size_t)(n0 + row) * K + kb + c8 * 8];
            }
            __syncthreads();

            bf16x8 bfr[2];
#pragma unroll
            for (int kc = 0; kc < 2; ++kc)
                bfr[kc] = *(const bf16x8*)&Bs[(w * 16 + col) * 72 + kc * 32 + q * 8];
#pragma unroll
            for (int f = 0; f < 4; ++f)
#pragma unroll
                for (int kc = 0; kc < 2; ++kc) {
                    bf16x8 af = *(const bf16x8*)&As[(f * 16 + col) * 72 + kc * 32 + q * 8];
                    acc[f] = __builtin_amdgcn_mfma_f32_16x16x32_bf16(af, bfr[kc], acc[f], 0, 0, 0);
                }
            __syncthreads();
        }

        int n = n0 + w * 16 + col;
        float bn = bias[n];
#pragma unroll
        for (int f = 0; f < 4; ++f)
#pragma unroll
            for (int rr = 0; rr < 4; ++rr) {
                int m = m0 + f * 16 + q * 4 + rr;
                e_bf16[(size_t)m * 768 + z * 256 + n] = f2bf(acc[f][rr] + bn);
            }
    } else {
        // ---------- kuramoto ----------
        short (*cs)[2][16][208] = (short (*)[2][16][208])smem;      // 26624 B
        float (*Rl)[3] = (float (*)[3])(smem + 26624);              // 192 B

        int m0 = (b - 384) * 16;

        bf16x8 kb[3][6];
#pragma unroll
        for (int ntl = 0; ntl < 3; ++ntl)
#pragma unroll
            for (int kc = 0; kc < 6; ++kc) {
                int nt = w * 3 + ntl;
                kb[ntl][kc] = *(const bf16x8*)&Kp[((nt * 6 + kc) * 64 + lane) * 8];
            }

        float ph[3][4], om[3], c[3][4], s[3][4];
#pragma unroll
        for (int ntl = 0; ntl < 3; ++ntl) {
            int i = (w * 3 + ntl) * 16 + col;
            int z = i >> 6;
            int c0 = (z == 0) ? 0 : (z == 1 ? 4 : 10);
            int nch = (z == 0) ? 4 : (z == 1 ? 6 : 8);
            om[ntl] = om_eff[i];
#pragma unroll
            for (int r = 0; r < 4; ++r) {
                float raw = bp_all[i];
                size_t base = (size_t)c0 * 131072 + (size_t)(m0 + q * 4 + r) * 64 + (i & 63);
#pragma unroll
                for (int cc = 0; cc < 8; ++cc)
                    if (cc < nch) raw += partial[base + (size_t)cc * 131072];
                raw *= INV_2PI;
                ph[ntl][r] = raw - floorf(raw);
            }
        }

        for (int step = 0; step < 10; ++step) {
            int p = step & 1;
#pragma unroll
            for (int ntl = 0; ntl < 3; ++ntl) {
                int i = (w * 3 + ntl) * 16 + col;
#pragma unroll
                for (int r = 0; r < 4; ++r) {
                    c[ntl][r] = __builtin_amdgcn_cosf(ph[ntl][r]);  // v_cos_f32: revolutions
                    s[ntl][r] = __builtin_amdgcn_sinf(ph[ntl][r]);
                    cs[p][0][q * 4 + r][i] = f2bf(c[ntl][r]);
                    cs[p][1][q * 4 + r][i] = f2bf(s[ntl][r]);
                }
            }
            __syncthreads();

            f32x4 aC[3], aS[3];
#pragma unroll
            for (int ntl = 0; ntl < 3; ++ntl)
#pragma unroll
                for (int r = 0; r < 4; ++r) { aC[ntl][r] = 0.f; aS[ntl][r] = 0.f; }

#pragma unroll
            for (int kc = 0; kc < 6; ++kc) {
                bf16x8 ac  = *(const bf16x8*)&cs[p][0][col][kc * 32 + q * 8];
                bf16x8 as_ = *(const bf16x8*)&cs[p][1][col][kc * 32 + q * 8];
#pragma unroll
                for (int ntl = 0; ntl < 3; ++ntl) {
                    aC[ntl] = __builtin_amdgcn_mfma_f32_16x16x32_bf16(ac,  kb[ntl][kc], aC[ntl], 0, 0, 0);
                    aS[ntl] = __builtin_amdgcn_mfma_f32_16x16x32_bf16(as_, kb[ntl][kc], aS[ntl], 0, 0, 0);
                }
            }

#pragma unroll
            for (int ntl = 0; ntl < 3; ++ntl)
#pragma unroll
                for (int r = 0; r < 4; ++r) {
                    float f = (s[ntl][r] * aC[ntl][r] - c[ntl][r] * aS[ntl][r]) * FSCALE;
                    float pn = ph[ntl][r] + om[ntl] + f;
                    ph[ntl][r] = pn - floorf(pn);
                }
            if (step < 9) __syncthreads();
        }

        __syncthreads();
#pragma unroll
        for (int ntl = 0; ntl < 3; ++ntl) {
            int i = (w * 3 + ntl) * 16 + col;
#pragma unroll
            for (int r = 0; r < 4; ++r) {
                float cp = __builtin_amdgcn_cosf(ph[ntl][r]);
                float sp = __builtin_amdgcn_sinf(ph[ntl][r]);
                cs[0][0][q * 4 + r][i] = f2bf(cp);
                cs[0][1][q * 4 + r][i] = f2bf(sp);
                phases_out[(size_t)(m0 + q * 4 + r) * 192 + i] = ph[ntl][r] * TWO_PI_F;
            }
        }
        __syncthreads();

        if (t < 48) {
            int r = t & 15, mod = t >> 4;
            float sc = 0.f, ss = 0.f;
#pragma unroll
            for (int g = 0; g < 8; ++g) {
                bf16x8 vc = *(const bf16x8*)&cs[0][0][r][mod * 64 + g * 8];
                bf16x8 vs = *(const bf16x8*)&cs[0][1][r][mod * 64 + g * 8];
#pragma unroll
                for (int j = 0; j < 8; ++j) { sc += bf2f(vc[j]); ss += bf2f(vs[j]); }
            }
            sc *= (1.f / 64.f); ss *= (1.f / 64.f);
            pm[(size_t)(m0 + r) * 3 + mod] = 0.5f + 0.5f * sc;
            Rl[r][mod] = sqrtf(sc * sc + ss * ss);
        }
        __syncthreads();
        if (t < 3) {
            int a = (t == 2) ? 1 : 0;
            int bb = (t == 0) ? 1 : 2;
            float accp = 0.f;
            for (int r = 0; r < 16; ++r) accp += Rl[r][a] * Rl[r][bb];
            atomicAdd(&bacc[t], accp);
        }
    }
}

// ============================ K3: fusion + finalize ============================
__global__ __launch_bounds__(256) void back_kernel(
    const short* __restrict__ e_bf16, const short* __restrict__ WB,
    const float* __restrict__ bias, const float* __restrict__ pm,
    const float* __restrict__ bacc,
    float* __restrict__ out_bound, float* __restrict__ out_bm, float* __restrict__ out_total)
{
    const short* Wfb = WB + 589824;   // Wfu slab (bf16)
    int m0 = blockIdx.x * 64, n0 = blockIdx.y * 64;
    int t = threadIdx.x;
    int lane = t & 63, w = t >> 6;
    int q = lane >> 4, col = lane & 15;

    __shared__ alignas(16) short As[64 * 72];
    __shared__ alignas(16) short Bs[64 * 72];

    f32x4 acc[4];
#pragma unroll
    for (int f = 0; f < 4; ++f)
#pragma unroll
        for (int r = 0; r < 4; ++r) acc[f][r] = 0.f;

    for (int kb = 0; kb < 768; kb += 64) {
#pragma unroll
        for (int p = 0; p < 2; ++p) {
            int u = t + 256 * p;
            int row = u >> 3, c8 = u & 7;
            int k = kb + c8 * 8;
            int mod = k >> 8;
            bf16x8 v = *(const bf16x8*)&e_bf16[(size_t)(m0 + row) * 768 + k];
            float sc = pm[(size_t)(m0 + row) * 3 + mod];
            bf16x8 h;
#pragma unroll
            for (int j = 0; j < 8; ++j) h[j] = f2bf(bf2f(v[j]) * sc);
            *(bf16x8*)&As[row * 72 + c8 * 8] = h;

            *(bf16x8*)&Bs[row * 72 + c8 * 8] = *(const bf16x8*)&Wfb[(size_t)(n0 + row) * 768 + k];
        }
        __syncthreads();

        bf16x8 bfr[2];
#pragma unroll
        for (int kc = 0; kc < 2; ++kc)
            bfr[kc] = *(const bf16x8*)&Bs[(w * 16 + col) * 72 + kc * 32 + q * 8];
#pragma unroll
        for (int f = 0; f < 4; ++f)
#pragma unroll
            for (int kc = 0; kc < 2; ++kc) {
                bf16x8 af = *(const bf16x8*)&As[(f * 16 + col) * 72 + kc * 32 + q * 8];
                acc[f] = __builtin_amdgcn_mfma_f32_16x16x32_bf16(af, bfr[kc], acc[f], 0, 0, 0);
            }
        __syncthreads();
    }

    int n = n0 + w * 16 + col;
    float bn = bias[n];
#pragma unroll
    for (int f = 0; f < 4; ++f)
#pragma unroll
        for (int r = 0; r < 4; ++r) {
            int m = m0 + f * 16 + q * 4 + r;
            out_bound[(size_t)m * 256 + n] = acc[f][r] + bn;
        }

    if (blockIdx.x == 0 && blockIdx.y == 0) {
        float p01 = bacc[0] * (1.f / 2048.f);
        float p02 = bacc[1] * (1.f / 2048.f);
        float p12 = bacc[2] * (1.f / 2048.f);
        float total = (p01 + p02 + p12) * (1.f / 3.f);
        if (t == 0) {
            out_bm[0] = 1.f; out_bm[1] = p01; out_bm[2] = p02;
            out_bm[3] = p01; out_bm[4] = 1.f; out_bm[5] = p12;
            out_bm[6] = p02; out_bm[7] = p12; out_bm[8] = 1.f;
        }
        for (int i = t; i < 2048; i += 256) out_total[i] = total;
    }
}

// ============================ launch ============================
extern "C" void kernel_launch(void* const* d_in, const int* in_sizes, int n_in,
                              void* d_out, int out_size, void* d_ws, size_t ws_size,
                              hipStream_t stream)
{
    const float* x_a  = (const float*)d_in[0];
    const float* Wf_a = (const float*)d_in[1];
    const float* bf_a = (const float*)d_in[2];
    const float* Wp_a = (const float*)d_in[3];
    const float* bp_a = (const float*)d_in[4];
    const float* x_t  = (const float*)d_in[5];
    const float* Wf_t = (const float*)d_in[6];
    const float* bf_t = (const float*)d_in[7];
    const float* Wp_t = (const float*)d_in[8];
    const float* bp_t = (const float*)d_in[9];
    const float* x_v  = (const float*)d_in[10];
    const float* Wf_v = (const float*)d_in[11];
    const float* bf_v = (const float*)d_in[12];
    const float* Wp_v = (const float*)d_in[13];
    const float* bp_v = (const float*)d_in[14];
    const float* om_a = (const float*)d_in[15];
    const float* om_t = (const float*)d_in[16];
    const float* om_v = (const float*)d_in[17];
    const float* IC   = (const float*)d_in[18];
    const float* Wfu  = (const float*)d_in[19];
    const float* bfu  = (const float*)d_in[20];

    float* ws      = (float*)d_ws;
    float* omw     = ws;                        // 256
    float* bpw     = ws + 256;                  // 256
    float* pmv     = ws + 512;                  // 6144
    float* baccw   = ws + 6656;                 // 64
    float* partial = ws + 6720;                 // 18*131072 = 2359296
    short* e_bf    = (short*)(ws + 2366016);    // 1572864 shorts
    short* XB      = (short*)(ws + 3152448);    // 4718592 shorts (x concat bf16)
    short* WB      = (short*)(ws + 5511744);    // 786432 shorts (Wf a|t|v|Wfu bf16)
    short* Kpck    = (short*)(ws + 5904960);    // 36864 shorts

    float* out        = (float*)d_out;
    float* out_bound  = out;           // 2048*256
    float* out_bm     = out + 524288;  // 9
    float* out_phases = out + 524297;  // 2048*192
    float* out_total  = out + 917513;  // 2048

    front_kernel<<<405, 256, 0, stream>>>(
        x_a, x_t, x_v, Wp_a, Wp_t, Wp_v, Wf_a, Wf_t, Wf_v, Wfu,
        IC, om_a, om_t, om_v, bp_a, bp_t, bp_v,
        partial, XB, WB, Kpck, omw, bpw, baccw);

    mid_kernel<<<512, 256, 0, stream>>>(
        XB, WB, bf_a, bf_t, bf_v,
        partial, bpw, Kpck, omw,
        e_bf, out_phases, pmv, baccw);

    dim3 gF(32, 4);
    back_kernel<<<gF, 256, 0, stream>>>(e_bf, WB, bfu, pmv, baccw,
                                        out_bound, out_bm, out_total);
}

// Round 7
// 168.092 us; speedup vs baseline: 3.1920x; 1.0515x over previous
//
#include <hip/hip_runtime.h>
#include <math.h>

typedef short bf16x8 __attribute__((ext_vector_type(8)));
typedef short bf16x4 __attribute__((ext_vector_type(4)));
typedef float f32x4  __attribute__((ext_vector_type(4)));

#define INV_2PI  0.15915494309189535f
#define TWO_PI_F 6.283185307179586f
// DT/(2*pi)/N = 0.01/(2*pi)/192
#define FSCALE   8.2893199e-06f

static __device__ inline short f2bf(float f) {
    union { float f; unsigned u; } v; v.f = f;
    unsigned r = (v.u + 0x7FFFu + ((v.u >> 16) & 1u)) >> 16;
    return (short)r;
}
static __device__ inline float bf2f(short h) {
    union { unsigned u; float f; } v; v.u = ((unsigned)(unsigned short)h) << 16;
    return v.f;
}

// ============================ K1: front ============================
// [0,576):   phase split-K partials fp32: 64 rows x 64 cols x 128-K chunk,
//            (18 slots x 32 row-blocks), 4x4 micro-tile, reg double-buffered
// [576,648): x fp32->bf16 convert into XB concat
// [648,680): Kp pack (bf16 B-frag layout)
// 680:       omega/bias/bacc
__global__ __launch_bounds__(256) void front_kernel(
    const float* __restrict__ xa, const float* __restrict__ xt, const float* __restrict__ xv,
    const float* __restrict__ Wpa, const float* __restrict__ Wpt, const float* __restrict__ Wpv,
    const float* __restrict__ IC,
    const float* __restrict__ oa, const float* __restrict__ ot, const float* __restrict__ ov,
    const float* __restrict__ bpa, const float* __restrict__ bpt, const float* __restrict__ bpv,
    float* __restrict__ partial, short* __restrict__ XB, short* __restrict__ Kp,
    float* __restrict__ om_eff, float* __restrict__ bp_all, float* __restrict__ bacc)
{
    __shared__ alignas(16) float As[16][72];
    __shared__ alignas(16) float Bs[16][72];
    int b = blockIdx.x;
    int t = threadIdx.x;

    if (b < 576) {
        // ---------- phase partial ----------
        int slot = b % 18, rb = b / 18;
        int z = slot < 4 ? 0 : (slot < 10 ? 1 : 2);
        int chunk = slot - (z == 0 ? 0 : (z == 1 ? 4 : 10));
        const float* A = z == 0 ? xa : (z == 1 ? xt : xv);
        const float* W = z == 0 ? Wpa : (z == 1 ? Wpt : Wpv);
        int K = z == 0 ? 512 : (z == 1 ? 768 : 1024);
        int kb = chunk * 128;
        int m0 = rb * 64;

        int tx = t & 15, ty = t >> 4;
        int row = t >> 2, c4 = t & 3;

        float acc[4][4] = {};
        // prefetch regs for k0 = 0
        float4 ar = *(const float4*)&A[(size_t)(m0 + row) * K + kb + c4 * 4];
        float4 br = *(const float4*)&W[(size_t)row * K + kb + c4 * 4];

        for (int k0 = 0; k0 < 128; k0 += 16) {
            if (k0) __syncthreads();          // LDS free (prev compute done)
            As[c4 * 4 + 0][row] = ar.x;
            As[c4 * 4 + 1][row] = ar.y;
            As[c4 * 4 + 2][row] = ar.z;
            As[c4 * 4 + 3][row] = ar.w;
            Bs[c4 * 4 + 0][row] = br.x;
            Bs[c4 * 4 + 1][row] = br.y;
            Bs[c4 * 4 + 2][row] = br.z;
            Bs[c4 * 4 + 3][row] = br.w;
            __syncthreads();
            if (k0 + 16 < 128) {              // issue next loads before compute
                ar = *(const float4*)&A[(size_t)(m0 + row) * K + kb + k0 + 16 + c4 * 4];
                br = *(const float4*)&W[(size_t)row * K + kb + k0 + 16 + c4 * 4];
            }
#pragma unroll
            for (int kk = 0; kk < 16; ++kk) {
                float4 aq = *(const float4*)&As[kk][ty * 4];
                float4 bq = *(const float4*)&Bs[kk][tx * 4];
                float av[4] = {aq.x, aq.y, aq.z, aq.w};
                float bv[4] = {bq.x, bq.y, bq.z, bq.w};
#pragma unroll
                for (int i = 0; i < 4; ++i)
#pragma unroll
                    for (int j = 0; j < 4; ++j)
                        acc[i][j] += av[i] * bv[j];
            }
        }

        float* P = partial + (size_t)slot * 131072;
#pragma unroll
        for (int i = 0; i < 4; ++i) {
            float4 v = make_float4(acc[i][0], acc[i][1], acc[i][2], acc[i][3]);
            *(float4*)&P[(size_t)(m0 + ty * 4 + i) * 64 + tx * 4] = v;
        }
    } else if (b < 648) {
        // ---------- x fp32 -> bf16 convert (f4 units, concat a|t|v) ----------
        for (int u = (b - 576) * 256 + t; u < 1179648; u += 72 * 256) {
            const float4* sp;
            if (u < 262144)      sp = (const float4*)xa + u;
            else if (u < 655360) sp = (const float4*)xt + (u - 262144);
            else                 sp = (const float4*)xv + (u - 655360);
            float4 v = *sp;
            bf16x4 h; h[0] = f2bf(v.x); h[1] = f2bf(v.y); h[2] = f2bf(v.z); h[3] = f2bf(v.w);
            *(bf16x4*)(XB + (size_t)u * 4) = h;
        }
    } else if (b < 680) {
        // ---------- Kp pack: B-frag 16x16x32 layout ----------
        for (int idx = (b - 648) * 256 + t; idx < 36864; idx += 32 * 256) {
            int k = idx / 192, n = idx - k * 192;
            float v = 0.5f * (IC[k * 192 + n] + IC[n * 192 + k]);
            int nt = n >> 4, kc = k >> 5;
            int lane = ((k >> 3) & 3) * 16 + (n & 15);
            int j = k & 7;
            Kp[((nt * 6 + kc) * 64 + lane) * 8 + j] = f2bf(v);
        }
    } else {
        if (t < 192) {
            float w = t < 64 ? oa[t] : (t < 128 ? ot[t - 64] : ov[t - 128]);
            om_eff[t] = w * (0.01f * INV_2PI);
            float bb = t < 64 ? bpa[t] : (t < 128 ? bpt[t - 64] : bpv[t - 128]);
            bp_all[t] = bb;
        }
        if (t < 4) bacc[t] = 0.f;
    }
}

// ============================ K2: encode + kuramoto ============================
// [0,384):   encode GEMM bf16 MFMA 64x64, BK=64, A = XB bf16 (two-pass staging!),
//            B = Wf fp32->bf16 in staging, reg double-buffered
// [384,512): kuramoto (16 rows/block), folds split-K phase reduction at init
__global__ __launch_bounds__(256) void mid_kernel(
    const short* __restrict__ XB,
    const float* __restrict__ Wfa, const float* __restrict__ Wft, const float* __restrict__ Wfv,
    const float* __restrict__ ba, const float* __restrict__ bt, const float* __restrict__ bv,
    const float* __restrict__ partial, const float* __restrict__ bp_all,
    const short* __restrict__ Kp, const float* __restrict__ om_eff,
    short* __restrict__ e_bf16,
    float* __restrict__ phases_out, float* __restrict__ pm, float* __restrict__ bacc)
{
    __shared__ alignas(16) char smem[26816];
    int b = blockIdx.x;
    int t = threadIdx.x;
    int lane = t & 63, w = t >> 6;
    int q = lane >> 4, col = lane & 15;

    if (b < 384) {
        // ---------- encode ----------
        int z = b / 128, r = b % 128;
        int m0 = (r >> 2) * 64, n0 = (r & 3) * 64;
        const short* A    = XB + (z == 0 ? 0 : (z == 1 ? 1048576 : 2621440));
        const float* W    = z == 0 ? Wfa : (z == 1 ? Wft : Wfv);
        const float* bias = z == 0 ? ba : (z == 1 ? bt : bv);
        int K             = z == 0 ? 512 : (z == 1 ? 768 : 1024);

        short* As = (short*)smem;            // [64][72]
        short* Bs = (short*)smem + 64 * 72;

        f32x4 acc[4];
#pragma unroll
        for (int f = 0; f < 4; ++f)
#pragma unroll
            for (int rr = 0; rr < 4; ++rr) acc[f][rr] = 0.f;

        // prefetch kb=0  (A: TWO passes -> full 64 rows)
        bf16x8 av[2];
#pragma unroll
        for (int p = 0; p < 2; ++p) {
            int u = t + 256 * p;
            int arow = u >> 3, ac8 = u & 7;
            av[p] = *(const bf16x8*)&A[(size_t)(m0 + arow) * K + ac8 * 8];
        }
        float4 bv4[4];
#pragma unroll
        for (int p = 0; p < 4; ++p) {
            int u = t + 256 * p;
            int brow = u >> 4, bc4 = u & 15;
            bv4[p] = *(const float4*)&W[(size_t)(n0 + brow) * K + bc4 * 4];
        }

        for (int kb = 0; kb < K; kb += 64) {
            if (kb) __syncthreads();
#pragma unroll
            for (int p = 0; p < 2; ++p) {
                int u = t + 256 * p;
                int arow = u >> 3, ac8 = u & 7;
                *(bf16x8*)&As[arow * 72 + ac8 * 8] = av[p];
            }
#pragma unroll
            for (int p = 0; p < 4; ++p) {
                int u = t + 256 * p;
                int brow = u >> 4, bc4 = u & 15;
                bf16x4 h;
                h[0] = f2bf(bv4[p].x); h[1] = f2bf(bv4[p].y);
                h[2] = f2bf(bv4[p].z); h[3] = f2bf(bv4[p].w);
                *(bf16x4*)&Bs[brow * 72 + bc4 * 4] = h;
            }
            __syncthreads();
            if (kb + 64 < K) {
#pragma unroll
                for (int p = 0; p < 2; ++p) {
                    int u = t + 256 * p;
                    int arow = u >> 3, ac8 = u & 7;
                    av[p] = *(const bf16x8*)&A[(size_t)(m0 + arow) * K + kb + 64 + ac8 * 8];
                }
#pragma unroll
                for (int p = 0; p < 4; ++p) {
                    int u = t + 256 * p;
                    int brow = u >> 4, bc4 = u & 15;
                    bv4[p] = *(const float4*)&W[(size_t)(n0 + brow) * K + kb + 64 + bc4 * 4];
                }
            }

            bf16x8 bfr[2];
#pragma unroll
            for (int kc = 0; kc < 2; ++kc)
                bfr[kc] = *(const bf16x8*)&Bs[(w * 16 + col) * 72 + kc * 32 + q * 8];
#pragma unroll
            for (int f = 0; f < 4; ++f)
#pragma unroll
                for (int kc = 0; kc < 2; ++kc) {
                    bf16x8 af = *(const bf16x8*)&As[(f * 16 + col) * 72 + kc * 32 + q * 8];
                    acc[f] = __builtin_amdgcn_mfma_f32_16x16x32_bf16(af, bfr[kc], acc[f], 0, 0, 0);
                }
        }

        int n = n0 + w * 16 + col;
        float bn = bias[n];
#pragma unroll
        for (int f = 0; f < 4; ++f)
#pragma unroll
            for (int rr = 0; rr < 4; ++rr) {
                int m = m0 + f * 16 + q * 4 + rr;
                e_bf16[(size_t)m * 768 + z * 256 + n] = f2bf(acc[f][rr] + bn);
            }
    } else {
        // ---------- kuramoto ----------
        short (*cs)[2][16][208] = (short (*)[2][16][208])smem;      // 26624 B
        float (*Rl)[3] = (float (*)[3])(smem + 26624);              // 192 B

        int m0 = (b - 384) * 16;

        bf16x8 kb[3][6];
#pragma unroll
        for (int ntl = 0; ntl < 3; ++ntl)
#pragma unroll
            for (int kc = 0; kc < 6; ++kc) {
                int nt = w * 3 + ntl;
                kb[ntl][kc] = *(const bf16x8*)&Kp[((nt * 6 + kc) * 64 + lane) * 8];
            }

        float ph[3][4], om[3], c[3][4], s[3][4];
#pragma unroll
        for (int ntl = 0; ntl < 3; ++ntl) {
            int i = (w * 3 + ntl) * 16 + col;
            int z = i >> 6;
            int c0 = (z == 0) ? 0 : (z == 1 ? 4 : 10);
            int nch = (z == 0) ? 4 : (z == 1 ? 6 : 8);
            om[ntl] = om_eff[i];
#pragma unroll
            for (int r = 0; r < 4; ++r) {
                float raw = bp_all[i];
                size_t base = (size_t)c0 * 131072 + (size_t)(m0 + q * 4 + r) * 64 + (i & 63);
#pragma unroll
                for (int cc = 0; cc < 8; ++cc)
                    if (cc < nch) raw += partial[base + (size_t)cc * 131072];
                raw *= INV_2PI;
                ph[ntl][r] = raw - floorf(raw);
            }
        }

        for (int step = 0; step < 10; ++step) {
            int p = step & 1;
#pragma unroll
            for (int ntl = 0; ntl < 3; ++ntl) {
                int i = (w * 3 + ntl) * 16 + col;
#pragma unroll
                for (int r = 0; r < 4; ++r) {
                    c[ntl][r] = __builtin_amdgcn_cosf(ph[ntl][r]);  // v_cos_f32: revolutions
                    s[ntl][r] = __builtin_amdgcn_sinf(ph[ntl][r]);
                    cs[p][0][q * 4 + r][i] = f2bf(c[ntl][r]);
                    cs[p][1][q * 4 + r][i] = f2bf(s[ntl][r]);
                }
            }
            __syncthreads();

            f32x4 aC[3], aS[3];
#pragma unroll
            for (int ntl = 0; ntl < 3; ++ntl)
#pragma unroll
                for (int r = 0; r < 4; ++r) { aC[ntl][r] = 0.f; aS[ntl][r] = 0.f; }

#pragma unroll
            for (int kc = 0; kc < 6; ++kc) {
                bf16x8 ac  = *(const bf16x8*)&cs[p][0][col][kc * 32 + q * 8];
                bf16x8 as_ = *(const bf16x8*)&cs[p][1][col][kc * 32 + q * 8];
#pragma unroll
                for (int ntl = 0; ntl < 3; ++ntl) {
                    aC[ntl] = __builtin_amdgcn_mfma_f32_16x16x32_bf16(ac,  kb[ntl][kc], aC[ntl], 0, 0, 0);
                    aS[ntl] = __builtin_amdgcn_mfma_f32_16x16x32_bf16(as_, kb[ntl][kc], aS[ntl], 0, 0, 0);
                }
            }

#pragma unroll
            for (int ntl = 0; ntl < 3; ++ntl)
#pragma unroll
                for (int r = 0; r < 4; ++r) {
                    float f = (s[ntl][r] * aC[ntl][r] - c[ntl][r] * aS[ntl][r]) * FSCALE;
                    float pn = ph[ntl][r] + om[ntl] + f;
                    ph[ntl][r] = pn - floorf(pn);
                }
            if (step < 9) __syncthreads();
        }

        __syncthreads();
#pragma unroll
        for (int ntl = 0; ntl < 3; ++ntl) {
            int i = (w * 3 + ntl) * 16 + col;
#pragma unroll
            for (int r = 0; r < 4; ++r) {
                float cp = __builtin_amdgcn_cosf(ph[ntl][r]);
                float sp = __builtin_amdgcn_sinf(ph[ntl][r]);
                cs[0][0][q * 4 + r][i] = f2bf(cp);
                cs[0][1][q * 4 + r][i] = f2bf(sp);
                phases_out[(size_t)(m0 + q * 4 + r) * 192 + i] = ph[ntl][r] * TWO_PI_F;
            }
        }
        __syncthreads();

        if (t < 48) {
            int r = t & 15, mod = t >> 4;
            float sc = 0.f, ss = 0.f;
#pragma unroll
            for (int g = 0; g < 8; ++g) {
                bf16x8 vc = *(const bf16x8*)&cs[0][0][r][mod * 64 + g * 8];
                bf16x8 vs = *(const bf16x8*)&cs[0][1][r][mod * 64 + g * 8];
#pragma unroll
                for (int j = 0; j < 8; ++j) { sc += bf2f(vc[j]); ss += bf2f(vs[j]); }
            }
            sc *= (1.f / 64.f); ss *= (1.f / 64.f);
            pm[(size_t)(m0 + r) * 3 + mod] = 0.5f + 0.5f * sc;
            Rl[r][mod] = sqrtf(sc * sc + ss * ss);
        }
        __syncthreads();
        if (t < 3) {
            int a = (t == 2) ? 1 : 0;
            int bb = (t == 0) ? 1 : 2;
            float accp = 0.f;
            for (int r = 0; r < 16; ++r) accp += Rl[r][a] * Rl[r][bb];
            atomicAdd(&bacc[t], accp);
        }
    }
}

// ============================ K3: fusion + finalize ============================
// bound = (e * pm_scale) @ Wfu^T + b_fusion. 32x64 tiles, grid (64,4) = 256 blocks.
// Wfu converted fp32->bf16 in staging; reg double-buffered.
__global__ __launch_bounds__(256) void back_kernel(
    const short* __restrict__ e_bf16, const float* __restrict__ Wfu,
    const float* __restrict__ bias, const float* __restrict__ pm,
    const float* __restrict__ bacc,
    float* __restrict__ out_bound, float* __restrict__ out_bm, float* __restrict__ out_total)
{
    int m0 = blockIdx.x * 32, n0 = blockIdx.y * 64;
    int t = threadIdx.x;
    int lane = t & 63, w = t >> 6;
    int q = lane >> 4, col = lane & 15;

    __shared__ alignas(16) short As[32 * 72];
    __shared__ alignas(16) short Bs[64 * 72];

    int arow = t >> 3, ac8 = t & 7;   // 32 rows x 8 groups = 256 slots = 256 threads

    f32x4 acc[2];
#pragma unroll
    for (int f = 0; f < 2; ++f)
#pragma unroll
        for (int r = 0; r < 4; ++r) acc[f][r] = 0.f;

    // prefetch kb=0
    bf16x8 av = *(const bf16x8*)&e_bf16[(size_t)(m0 + arow) * 768 + ac8 * 8];
    float asc = pm[(size_t)(m0 + arow) * 3 + 0];
    float4 bv4[4];
#pragma unroll
    for (int p = 0; p < 4; ++p) {
        int u = t + 256 * p;
        int brow = u >> 4, bc4 = u & 15;
        bv4[p] = *(const float4*)&Wfu[(size_t)(n0 + brow) * 768 + bc4 * 4];
    }

    for (int kb = 0; kb < 768; kb += 64) {
        if (kb) __syncthreads();
        {
            bf16x8 h;
#pragma unroll
            for (int j = 0; j < 8; ++j) h[j] = f2bf(bf2f(av[j]) * asc);
            *(bf16x8*)&As[arow * 72 + ac8 * 8] = h;
        }
#pragma unroll
        for (int p = 0; p < 4; ++p) {
            int u = t + 256 * p;
            int brow = u >> 4, bc4 = u & 15;
            bf16x4 h;
            h[0] = f2bf(bv4[p].x); h[1] = f2bf(bv4[p].y);
            h[2] = f2bf(bv4[p].z); h[3] = f2bf(bv4[p].w);
            *(bf16x4*)&Bs[brow * 72 + bc4 * 4] = h;
        }
        __syncthreads();
        if (kb + 64 < 768) {
            int k = kb + 64;
            av = *(const bf16x8*)&e_bf16[(size_t)(m0 + arow) * 768 + k + ac8 * 8];
            asc = pm[(size_t)(m0 + arow) * 3 + (k >> 8)];
#pragma unroll
            for (int p = 0; p < 4; ++p) {
                int u = t + 256 * p;
                int brow = u >> 4, bc4 = u & 15;
                bv4[p] = *(const float4*)&Wfu[(size_t)(n0 + brow) * 768 + k + bc4 * 4];
            }
        }

        bf16x8 bfr[2];
#pragma unroll
        for (int kc = 0; kc < 2; ++kc)
            bfr[kc] = *(const bf16x8*)&Bs[(w * 16 + col) * 72 + kc * 32 + q * 8];
#pragma unroll
        for (int f = 0; f < 2; ++f)
#pragma unroll
            for (int kc = 0; kc < 2; ++kc) {
                bf16x8 af = *(const bf16x8*)&As[(f * 16 + col) * 72 + kc * 32 + q * 8];
                acc[f] = __builtin_amdgcn_mfma_f32_16x16x32_bf16(af, bfr[kc], acc[f], 0, 0, 0);
            }
    }

    int n = n0 + w * 16 + col;
    float bn = bias[n];
#pragma unroll
    for (int f = 0; f < 2; ++f)
#pragma unroll
        for (int r = 0; r < 4; ++r) {
            int m = m0 + f * 16 + q * 4 + r;
            out_bound[(size_t)m * 256 + n] = acc[f][r] + bn;
        }

    if (blockIdx.x == 0 && blockIdx.y == 0) {
        float p01 = bacc[0] * (1.f / 2048.f);
        float p02 = bacc[1] * (1.f / 2048.f);
        float p12 = bacc[2] * (1.f / 2048.f);
        float total = (p01 + p02 + p12) * (1.f / 3.f);
        if (t == 0) {
            out_bm[0] = 1.f; out_bm[1] = p01; out_bm[2] = p02;
            out_bm[3] = p01; out_bm[4] = 1.f; out_bm[5] = p12;
            out_bm[6] = p02; out_bm[7] = p12; out_bm[8] = 1.f;
        }
        for (int i = t; i < 2048; i += 256) out_total[i] = total;
    }
}

// ============================ launch ============================
extern "C" void kernel_launch(void* const* d_in, const int* in_sizes, int n_in,
                              void* d_out, int out_size, void* d_ws, size_t ws_size,
                              hipStream_t stream)
{
    const float* x_a  = (const float*)d_in[0];
    const float* Wf_a = (const float*)d_in[1];
    const float* bf_a = (const float*)d_in[2];
    const float* Wp_a = (const float*)d_in[3];
    const float* bp_a = (const float*)d_in[4];
    const float* x_t  = (const float*)d_in[5];
    const float* Wf_t = (const float*)d_in[6];
    const float* bf_t = (const float*)d_in[7];
    const float* Wp_t = (const float*)d_in[8];
    const float* bp_t = (const float*)d_in[9];
    const float* x_v  = (const float*)d_in[10];
    const float* Wf_v = (const float*)d_in[11];
    const float* bf_v = (const float*)d_in[12];
    const float* Wp_v = (const float*)d_in[13];
    const float* bp_v = (const float*)d_in[14];
    const float* om_a = (const float*)d_in[15];
    const float* om_t = (const float*)d_in[16];
    const float* om_v = (const float*)d_in[17];
    const float* IC   = (const float*)d_in[18];
    const float* Wfu  = (const float*)d_in[19];
    const float* bfu  = (const float*)d_in[20];

    float* ws      = (float*)d_ws;
    float* omw     = ws;                        // 256
    float* bpw     = ws + 256;                  // 256
    float* pmv     = ws + 512;                  // 6144
    float* baccw   = ws + 6656;                 // 64
    float* partial = ws + 6720;                 // 18*131072 = 2359296
    short* e_bf    = (short*)(ws + 2366016);    // 1572864 shorts
    short* XB      = (short*)(ws + 3152448);    // 4718592 shorts
    short* Kpck    = (short*)(ws + 5511744);    // 36864 shorts

    float* out        = (float*)d_out;
    float* out_bound  = out;           // 2048*256
    float* out_bm     = out + 524288;  // 9
    float* out_phases = out + 524297;  // 2048*192
    float* out_total  = out + 917513;  // 2048

    front_kernel<<<681, 256, 0, stream>>>(
        x_a, x_t, x_v, Wp_a, Wp_t, Wp_v,
        IC, om_a, om_t, om_v, bp_a, bp_t, bp_v,
        partial, XB, Kpck, omw, bpw, baccw);

    mid_kernel<<<512, 256, 0, stream>>>(
        XB, Wf_a, Wf_t, Wf_v, bf_a, bf_t, bf_v,
        partial, bpw, Kpck, omw,
        e_bf, out_phases, pmv, baccw);

    dim3 gF(64, 4);
    back_kernel<<<gF, 256, 0, stream>>>(e_bf, Wfu, bfu, pmv, baccw,
                                        out_bound, out_bm, out_total);
}

// Round 8
// 155.374 us; speedup vs baseline: 3.4533x; 1.0819x over previous
//
#include <hip/hip_runtime.h>
#include <math.h>

typedef short bf16x8 __attribute__((ext_vector_type(8)));
typedef short bf16x4 __attribute__((ext_vector_type(4)));
typedef float f32x4  __attribute__((ext_vector_type(4)));

#define INV_2PI  0.15915494309189535f
#define TWO_PI_F 6.283185307179586f
// DT/(2*pi)/N = 0.01/(2*pi)/192
#define FSCALE   8.2893199e-06f

static __device__ inline short f2bf(float f) {
    union { float f; unsigned u; } v; v.f = f;
    unsigned r = (v.u + 0x7FFFu + ((v.u >> 16) & 1u)) >> 16;
    return (short)r;
}
static __device__ inline float bf2f(short h) {
    union { unsigned u; float f; } v; v.u = ((unsigned)(unsigned short)h) << 16;
    return v.f;
}

// ============================ K1: front ============================
// [0,576):   phase split-K partials fp32 (64 rows x 64 cols x 128-K chunk,
//            18 slots x 32 row-blocks), reg double-buffered; FUSED: each block
//            also emits bf16(x) for its exclusive x-tile into XB.
// [576,600): Wf a|t|v + Wfu fp32->bf16 convert into WB concat
// [600,632): Kp pack (bf16 B-frag layout)
// 632:       omega/bias/bacc
__global__ __launch_bounds__(256) void front_kernel(
    const float* __restrict__ xa, const float* __restrict__ xt, const float* __restrict__ xv,
    const float* __restrict__ Wpa, const float* __restrict__ Wpt, const float* __restrict__ Wpv,
    const float* __restrict__ Wfa, const float* __restrict__ Wft, const float* __restrict__ Wfv,
    const float* __restrict__ Wfu,
    const float* __restrict__ IC,
    const float* __restrict__ oa, const float* __restrict__ ot, const float* __restrict__ ov,
    const float* __restrict__ bpa, const float* __restrict__ bpt, const float* __restrict__ bpv,
    float* __restrict__ partial, short* __restrict__ XB, short* __restrict__ WB,
    short* __restrict__ Kp,
    float* __restrict__ om_eff, float* __restrict__ bp_all, float* __restrict__ bacc)
{
    __shared__ alignas(16) float As[16][72];
    __shared__ alignas(16) float Bs[16][72];
    int b = blockIdx.x;
    int t = threadIdx.x;

    if (b < 576) {
        // ---------- phase partial + fused x->bf16 ----------
        int slot = b % 18, rb = b / 18;
        int z = slot < 4 ? 0 : (slot < 10 ? 1 : 2);
        int chunk = slot - (z == 0 ? 0 : (z == 1 ? 4 : 10));
        const float* A = z == 0 ? xa : (z == 1 ? xt : xv);
        const float* W = z == 0 ? Wpa : (z == 1 ? Wpt : Wpv);
        short* XBz = XB + (z == 0 ? 0 : (z == 1 ? 1048576 : 2621440));
        int K = z == 0 ? 512 : (z == 1 ? 768 : 1024);
        int kb = chunk * 128;
        int m0 = rb * 64;

        int tx = t & 15, ty = t >> 4;
        int row = t >> 2, c4 = t & 3;

        float acc[4][4] = {};
        // prefetch regs for k0 = 0
        float4 ar = *(const float4*)&A[(size_t)(m0 + row) * K + kb + c4 * 4];
        float4 br = *(const float4*)&W[(size_t)row * K + kb + c4 * 4];

        for (int k0 = 0; k0 < 128; k0 += 16) {
            if (k0) __syncthreads();          // LDS free (prev compute done)
            As[c4 * 4 + 0][row] = ar.x;
            As[c4 * 4 + 1][row] = ar.y;
            As[c4 * 4 + 2][row] = ar.z;
            As[c4 * 4 + 3][row] = ar.w;
            Bs[c4 * 4 + 0][row] = br.x;
            Bs[c4 * 4 + 1][row] = br.y;
            Bs[c4 * 4 + 2][row] = br.z;
            Bs[c4 * 4 + 3][row] = br.w;
            // fused bf16 emit of this block's exclusive x-tile (data already here)
            {
                bf16x4 h; h[0] = f2bf(ar.x); h[1] = f2bf(ar.y);
                h[2] = f2bf(ar.z); h[3] = f2bf(ar.w);
                *(bf16x4*)&XBz[(size_t)(m0 + row) * K + kb + k0 + c4 * 4] = h;
            }
            __syncthreads();
            if (k0 + 16 < 128) {              // issue next loads before compute
                ar = *(const float4*)&A[(size_t)(m0 + row) * K + kb + k0 + 16 + c4 * 4];
                br = *(const float4*)&W[(size_t)row * K + kb + k0 + 16 + c4 * 4];
            }
#pragma unroll
            for (int kk = 0; kk < 16; ++kk) {
                float4 aq = *(const float4*)&As[kk][ty * 4];
                float4 bq = *(const float4*)&Bs[kk][tx * 4];
                float av[4] = {aq.x, aq.y, aq.z, aq.w};
                float bv[4] = {bq.x, bq.y, bq.z, bq.w};
#pragma unroll
                for (int i = 0; i < 4; ++i)
#pragma unroll
                    for (int j = 0; j < 4; ++j)
                        acc[i][j] += av[i] * bv[j];
            }
        }

        float* P = partial + (size_t)slot * 131072;
#pragma unroll
        for (int i = 0; i < 4; ++i) {
            float4 v = make_float4(acc[i][0], acc[i][1], acc[i][2], acc[i][3]);
            *(float4*)&P[(size_t)(m0 + ty * 4 + i) * 64 + tx * 4] = v;
        }
    } else if (b < 600) {
        // ---------- W fp32->bf16 convert (f4 units; Wfa|Wft|Wfv|Wfu concat) ----------
        for (int u = (b - 576) * 256 + t; u < 196608; u += 24 * 256) {
            const float4* sp;
            if (u < 32768)       sp = (const float4*)Wfa + u;
            else if (u < 81920)  sp = (const float4*)Wft + (u - 32768);
            else if (u < 147456) sp = (const float4*)Wfv + (u - 81920);
            else                 sp = (const float4*)Wfu + (u - 147456);
            float4 v = *sp;
            bf16x4 h; h[0] = f2bf(v.x); h[1] = f2bf(v.y); h[2] = f2bf(v.z); h[3] = f2bf(v.w);
            *(bf16x4*)(WB + (size_t)u * 4) = h;
        }
    } else if (b < 632) {
        // ---------- Kp pack: B-frag 16x16x32 layout ----------
        for (int idx = (b - 600) * 256 + t; idx < 36864; idx += 32 * 256) {
            int k = idx / 192, n = idx - k * 192;
            float v = 0.5f * (IC[k * 192 + n] + IC[n * 192 + k]);
            int nt = n >> 4, kc = k >> 5;
            int lane = ((k >> 3) & 3) * 16 + (n & 15);
            int j = k & 7;
            Kp[((nt * 6 + kc) * 64 + lane) * 8 + j] = f2bf(v);
        }
    } else {
        if (t < 192) {
            float w = t < 64 ? oa[t] : (t < 128 ? ot[t - 64] : ov[t - 128]);
            om_eff[t] = w * (0.01f * INV_2PI);
            float bb = t < 64 ? bpa[t] : (t < 128 ? bpt[t - 64] : bpv[t - 128]);
            bp_all[t] = bb;
        }
        if (t < 4) bacc[t] = 0.f;
    }
}

// ============================ K2: encode + kuramoto ============================
// [0,384):   encode GEMM bf16 MFMA 64x64, BK=64; A = XB, B = WB (both bf16,
//            pure b128 staging), reg double-buffered
// [384,512): kuramoto (16 rows/block), folds split-K phase reduction at init
__global__ __launch_bounds__(256) void mid_kernel(
    const short* __restrict__ XB, const short* __restrict__ WB,
    const float* __restrict__ ba, const float* __restrict__ bt, const float* __restrict__ bv,
    const float* __restrict__ partial, const float* __restrict__ bp_all,
    const short* __restrict__ Kp, const float* __restrict__ om_eff,
    short* __restrict__ e_bf16,
    float* __restrict__ phases_out, float* __restrict__ pm, float* __restrict__ bacc)
{
    __shared__ alignas(16) char smem[26816];
    int b = blockIdx.x;
    int t = threadIdx.x;
    int lane = t & 63, w = t >> 6;
    int q = lane >> 4, col = lane & 15;

    if (b < 384) {
        // ---------- encode ----------
        int z = b / 128, r = b % 128;
        int m0 = (r >> 2) * 64, n0 = (r & 3) * 64;
        const short* A    = XB + (z == 0 ? 0 : (z == 1 ? 1048576 : 2621440));
        const short* W    = WB + (z == 0 ? 0 : (z == 1 ? 131072 : 327680));
        const float* bias = z == 0 ? ba : (z == 1 ? bt : bv);
        int K             = z == 0 ? 512 : (z == 1 ? 768 : 1024);

        short* As = (short*)smem;            // [64][72]
        short* Bs = (short*)smem + 64 * 72;

        int srow = t >> 3, sc8 = t & 7;      // staging: 32 rows x 8 groups per pass

        f32x4 acc[4];
#pragma unroll
        for (int f = 0; f < 4; ++f)
#pragma unroll
            for (int rr = 0; rr < 4; ++rr) acc[f][rr] = 0.f;

        // prefetch kb=0 (two passes each -> full 64 rows)
        bf16x8 av[2], bv8[2];
#pragma unroll
        for (int p = 0; p < 2; ++p) {
            av[p]  = *(const bf16x8*)&A[(size_t)(m0 + srow + 32 * p) * K + sc8 * 8];
            bv8[p] = *(const bf16x8*)&W[(size_t)(n0 + srow + 32 * p) * K + sc8 * 8];
        }

        for (int kb = 0; kb < K; kb += 64) {
            if (kb) __syncthreads();
#pragma unroll
            for (int p = 0; p < 2; ++p) {
                *(bf16x8*)&As[(srow + 32 * p) * 72 + sc8 * 8] = av[p];
                *(bf16x8*)&Bs[(srow + 32 * p) * 72 + sc8 * 8] = bv8[p];
            }
            __syncthreads();
            if (kb + 64 < K) {
#pragma unroll
                for (int p = 0; p < 2; ++p) {
                    av[p]  = *(const bf16x8*)&A[(size_t)(m0 + srow + 32 * p) * K + kb + 64 + sc8 * 8];
                    bv8[p] = *(const bf16x8*)&W[(size_t)(n0 + srow + 32 * p) * K + kb + 64 + sc8 * 8];
                }
            }

            bf16x8 bfr[2];
#pragma unroll
            for (int kc = 0; kc < 2; ++kc)
                bfr[kc] = *(const bf16x8*)&Bs[(w * 16 + col) * 72 + kc * 32 + q * 8];
#pragma unroll
            for (int f = 0; f < 4; ++f)
#pragma unroll
                for (int kc = 0; kc < 2; ++kc) {
                    bf16x8 af = *(const bf16x8*)&As[(f * 16 + col) * 72 + kc * 32 + q * 8];
                    acc[f] = __builtin_amdgcn_mfma_f32_16x16x32_bf16(af, bfr[kc], acc[f], 0, 0, 0);
                }
        }

        int n = n0 + w * 16 + col;
        float bn = bias[n];
#pragma unroll
        for (int f = 0; f < 4; ++f)
#pragma unroll
            for (int rr = 0; rr < 4; ++rr) {
                int m = m0 + f * 16 + q * 4 + rr;
                e_bf16[(size_t)m * 768 + z * 256 + n] = f2bf(acc[f][rr] + bn);
            }
    } else {
        // ---------- kuramoto ----------
        short (*cs)[2][16][208] = (short (*)[2][16][208])smem;      // 26624 B
        float (*Rl)[3] = (float (*)[3])(smem + 26624);              // 192 B

        int m0 = (b - 384) * 16;

        bf16x8 kb[3][6];
#pragma unroll
        for (int ntl = 0; ntl < 3; ++ntl)
#pragma unroll
            for (int kc = 0; kc < 6; ++kc) {
                int nt = w * 3 + ntl;
                kb[ntl][kc] = *(const bf16x8*)&Kp[((nt * 6 + kc) * 64 + lane) * 8];
            }

        float ph[3][4], om[3], c[3][4], s[3][4];
#pragma unroll
        for (int ntl = 0; ntl < 3; ++ntl) {
            int i = (w * 3 + ntl) * 16 + col;
            int z = i >> 6;
            int c0 = (z == 0) ? 0 : (z == 1 ? 4 : 10);
            int nch = (z == 0) ? 4 : (z == 1 ? 6 : 8);
            om[ntl] = om_eff[i];
#pragma unroll
            for (int r = 0; r < 4; ++r) {
                float raw = bp_all[i];
                size_t base = (size_t)c0 * 131072 + (size_t)(m0 + q * 4 + r) * 64 + (i & 63);
#pragma unroll
                for (int cc = 0; cc < 8; ++cc)
                    if (cc < nch) raw += partial[base + (size_t)cc * 131072];
                raw *= INV_2PI;
                ph[ntl][r] = raw - floorf(raw);
            }
        }

        for (int step = 0; step < 10; ++step) {
            int p = step & 1;
#pragma unroll
            for (int ntl = 0; ntl < 3; ++ntl) {
                int i = (w * 3 + ntl) * 16 + col;
#pragma unroll
                for (int r = 0; r < 4; ++r) {
                    c[ntl][r] = __builtin_amdgcn_cosf(ph[ntl][r]);  // v_cos_f32: revolutions
                    s[ntl][r] = __builtin_amdgcn_sinf(ph[ntl][r]);
                    cs[p][0][q * 4 + r][i] = f2bf(c[ntl][r]);
                    cs[p][1][q * 4 + r][i] = f2bf(s[ntl][r]);
                }
            }
            __syncthreads();

            f32x4 aC[3], aS[3];
#pragma unroll
            for (int ntl = 0; ntl < 3; ++ntl)
#pragma unroll
                for (int r = 0; r < 4; ++r) { aC[ntl][r] = 0.f; aS[ntl][r] = 0.f; }

#pragma unroll
            for (int kc = 0; kc < 6; ++kc) {
                bf16x8 ac  = *(const bf16x8*)&cs[p][0][col][kc * 32 + q * 8];
                bf16x8 as_ = *(const bf16x8*)&cs[p][1][col][kc * 32 + q * 8];
#pragma unroll
                for (int ntl = 0; ntl < 3; ++ntl) {
                    aC[ntl] = __builtin_amdgcn_mfma_f32_16x16x32_bf16(ac,  kb[ntl][kc], aC[ntl], 0, 0, 0);
                    aS[ntl] = __builtin_amdgcn_mfma_f32_16x16x32_bf16(as_, kb[ntl][kc], aS[ntl], 0, 0, 0);
                }
            }

#pragma unroll
            for (int ntl = 0; ntl < 3; ++ntl)
#pragma unroll
                for (int r = 0; r < 4; ++r) {
                    float f = (s[ntl][r] * aC[ntl][r] - c[ntl][r] * aS[ntl][r]) * FSCALE;
                    float pn = ph[ntl][r] + om[ntl] + f;
                    ph[ntl][r] = pn - floorf(pn);
                }
            if (step < 9) __syncthreads();
        }

        __syncthreads();
#pragma unroll
        for (int ntl = 0; ntl < 3; ++ntl) {
            int i = (w * 3 + ntl) * 16 + col;
#pragma unroll
            for (int r = 0; r < 4; ++r) {
                float cp = __builtin_amdgcn_cosf(ph[ntl][r]);
                float sp = __builtin_amdgcn_sinf(ph[ntl][r]);
                cs[0][0][q * 4 + r][i] = f2bf(cp);
                cs[0][1][q * 4 + r][i] = f2bf(sp);
                phases_out[(size_t)(m0 + q * 4 + r) * 192 + i] = ph[ntl][r] * TWO_PI_F;
            }
        }
        __syncthreads();

        if (t < 48) {
            int r = t & 15, mod = t >> 4;
            float sc = 0.f, ss = 0.f;
#pragma unroll
            for (int g = 0; g < 8; ++g) {
                bf16x8 vc = *(const bf16x8*)&cs[0][0][r][mod * 64 + g * 8];
                bf16x8 vs = *(const bf16x8*)&cs[0][1][r][mod * 64 + g * 8];
#pragma unroll
                for (int j = 0; j < 8; ++j) { sc += bf2f(vc[j]); ss += bf2f(vs[j]); }
            }
            sc *= (1.f / 64.f); ss *= (1.f / 64.f);
            pm[(size_t)(m0 + r) * 3 + mod] = 0.5f + 0.5f * sc;
            Rl[r][mod] = sqrtf(sc * sc + ss * ss);
        }
        __syncthreads();
        if (t < 3) {
            int a = (t == 2) ? 1 : 0;
            int bb = (t == 0) ? 1 : 2;
            float accp = 0.f;
            for (int r = 0; r < 16; ++r) accp += Rl[r][a] * Rl[r][bb];
            atomicAdd(&bacc[t], accp);
        }
    }
}

// ============================ K3: fusion + finalize ============================
// bound = (e * pm_scale) @ Wfu^T + b_fusion. 32x64 tiles, grid (64,4) = 256 blocks.
// B from WB bf16 (pure b128 staging); reg double-buffered.
__global__ __launch_bounds__(256) void back_kernel(
    const short* __restrict__ e_bf16, const short* __restrict__ WB,
    const float* __restrict__ bias, const float* __restrict__ pm,
    const float* __restrict__ bacc,
    float* __restrict__ out_bound, float* __restrict__ out_bm, float* __restrict__ out_total)
{
    const short* Wfb = WB + 589824;   // Wfu slab (bf16)
    int m0 = blockIdx.x * 32, n0 = blockIdx.y * 64;
    int t = threadIdx.x;
    int lane = t & 63, w = t >> 6;
    int q = lane >> 4, col = lane & 15;

    __shared__ alignas(16) short As[32 * 72];
    __shared__ alignas(16) short Bs[64 * 72];

    int srow = t >> 3, sc8 = t & 7;   // A: 32 rows x 8 groups; B: two passes

    f32x4 acc[2];
#pragma unroll
    for (int f = 0; f < 2; ++f)
#pragma unroll
        for (int r = 0; r < 4; ++r) acc[f][r] = 0.f;

    // prefetch kb=0
    bf16x8 av = *(const bf16x8*)&e_bf16[(size_t)(m0 + srow) * 768 + sc8 * 8];
    float asc = pm[(size_t)(m0 + srow) * 3 + 0];
    bf16x8 bv8[2];
#pragma unroll
    for (int p = 0; p < 2; ++p)
        bv8[p] = *(const bf16x8*)&Wfb[(size_t)(n0 + srow + 32 * p) * 768 + sc8 * 8];

    for (int kb = 0; kb < 768; kb += 64) {
        if (kb) __syncthreads();
        {
            bf16x8 h;
#pragma unroll
            for (int j = 0; j < 8; ++j) h[j] = f2bf(bf2f(av[j]) * asc);
            *(bf16x8*)&As[srow * 72 + sc8 * 8] = h;
        }
#pragma unroll
        for (int p = 0; p < 2; ++p)
            *(bf16x8*)&Bs[(srow + 32 * p) * 72 + sc8 * 8] = bv8[p];
        __syncthreads();
        if (kb + 64 < 768) {
            int k = kb + 64;
            av = *(const bf16x8*)&e_bf16[(size_t)(m0 + srow) * 768 + k + sc8 * 8];
            asc = pm[(size_t)(m0 + srow) * 3 + (k >> 8)];
#pragma unroll
            for (int p = 0; p < 2; ++p)
                bv8[p] = *(const bf16x8*)&Wfb[(size_t)(n0 + srow + 32 * p) * 768 + k + sc8 * 8];
        }

        bf16x8 bfr[2];
#pragma unroll
        for (int kc = 0; kc < 2; ++kc)
            bfr[kc] = *(const bf16x8*)&Bs[(w * 16 + col) * 72 + kc * 32 + q * 8];
#pragma unroll
        for (int f = 0; f < 2; ++f)
#pragma unroll
            for (int kc = 0; kc < 2; ++kc) {
                bf16x8 af = *(const bf16x8*)&As[(f * 16 + col) * 72 + kc * 32 + q * 8];
                acc[f] = __builtin_amdgcn_mfma_f32_16x16x32_bf16(af, bfr[kc], acc[f], 0, 0, 0);
            }
    }

    int n = n0 + w * 16 + col;
    float bn = bias[n];
#pragma unroll
    for (int f = 0; f < 2; ++f)
#pragma unroll
        for (int r = 0; r < 4; ++r) {
            int m = m0 + f * 16 + q * 4 + r;
            out_bound[(size_t)m * 256 + n] = acc[f][r] + bn;
        }

    if (blockIdx.x == 0 && blockIdx.y == 0) {
        float p01 = bacc[0] * (1.f / 2048.f);
        float p02 = bacc[1] * (1.f / 2048.f);
        float p12 = bacc[2] * (1.f / 2048.f);
        float total = (p01 + p02 + p12) * (1.f / 3.f);
        if (t == 0) {
            out_bm[0] = 1.f; out_bm[1] = p01; out_bm[2] = p02;
            out_bm[3] = p01; out_bm[4] = 1.f; out_bm[5] = p12;
            out_bm[6] = p02; out_bm[7] = p12; out_bm[8] = 1.f;
        }
        for (int i = t; i < 2048; i += 256) out_total[i] = total;
    }
}

// ============================ launch ============================
extern "C" void kernel_launch(void* const* d_in, const int* in_sizes, int n_in,
                              void* d_out, int out_size, void* d_ws, size_t ws_size,
                              hipStream_t stream)
{
    const float* x_a  = (const float*)d_in[0];
    const float* Wf_a = (const float*)d_in[1];
    const float* bf_a = (const float*)d_in[2];
    const float* Wp_a = (const float*)d_in[3];
    const float* bp_a = (const float*)d_in[4];
    const float* x_t  = (const float*)d_in[5];
    const float* Wf_t = (const float*)d_in[6];
    const float* bf_t = (const float*)d_in[7];
    const float* Wp_t = (const float*)d_in[8];
    const float* bp_t = (const float*)d_in[9];
    const float* x_v  = (const float*)d_in[10];
    const float* Wf_v = (const float*)d_in[11];
    const float* bf_v = (const float*)d_in[12];
    const float* Wp_v = (const float*)d_in[13];
    const float* bp_v = (const float*)d_in[14];
    const float* om_a = (const float*)d_in[15];
    const float* om_t = (const float*)d_in[16];
    const float* om_v = (const float*)d_in[17];
    const float* IC   = (const float*)d_in[18];
    const float* Wfu  = (const float*)d_in[19];
    const float* bfu  = (const float*)d_in[20];

    float* ws      = (float*)d_ws;
    float* omw     = ws;                        // 256
    float* bpw     = ws + 256;                  // 256
    float* pmv     = ws + 512;                  // 6144
    float* baccw   = ws + 6656;                 // 64
    float* partial = ws + 6720;                 // 18*131072 = 2359296
    short* e_bf    = (short*)(ws + 2366016);    // 1572864 shorts
    short* XB      = (short*)(ws + 3152448);    // 4718592 shorts
    short* Kpck    = (short*)(ws + 5511744);    // 36864 shorts
    short* WB      = (short*)(ws + 5530176);    // 786432 shorts

    float* out        = (float*)d_out;
    float* out_bound  = out;           // 2048*256
    float* out_bm     = out + 524288;  // 9
    float* out_phases = out + 524297;  // 2048*192
    float* out_total  = out + 917513;  // 2048

    front_kernel<<<633, 256, 0, stream>>>(
        x_a, x_t, x_v, Wp_a, Wp_t, Wp_v, Wf_a, Wf_t, Wf_v, Wfu,
        IC, om_a, om_t, om_v, bp_a, bp_t, bp_v,
        partial, XB, WB, Kpck, omw, bpw, baccw);

    mid_kernel<<<512, 256, 0, stream>>>(
        XB, WB, bf_a, bf_t, bf_v,
        partial, bpw, Kpck, omw,
        e_bf, out_phases, pmv, baccw);

    dim3 gF(64, 4);
    back_kernel<<<gF, 256, 0, stream>>>(e_bf, WB, bfu, pmv, baccw,
                                        out_bound, out_bm, out_total);
}